// Round 1
// baseline (889.550 us; speedup 1.0000x reference)
//
#include <hip/hip_runtime.h>
#include <math.h>

#define N_NODES 50000
#define N_EDGES 640000
#define F_INDIM 64
#define HDIM 128
#define NLAYERS 3
#define NGRAPH 64
#define NCLS 2

// ---------------- init / degree / CSR build ----------------

__global__ __launch_bounds__(256) void k_init(int* hist, float* pool, float* counts) {
    int i = blockIdx.x * 256 + threadIdx.x;
    if (i < N_NODES) hist[i] = 0;
    if (i < NGRAPH * HDIM) pool[i] = 0.f;
    if (i < NGRAPH) counts[i] = 0.f;
}

__global__ __launch_bounds__(256) void k_hist(const int* __restrict__ dst, int* __restrict__ hist) {
    int e = blockIdx.x * 256 + threadIdx.x;
    if (e < N_EDGES) atomicAdd(&hist[dst[e]], 1);
}

__global__ __launch_bounds__(256) void k_dis(const int* __restrict__ hist, float* __restrict__ dis) {
    int i = blockIdx.x * 256 + threadIdx.x;
    if (i < N_NODES) dis[i] = rsqrtf((float)hist[i] + 1.0f);
}

// single-block exclusive scan of hist -> row_start (+cursor copy); row_start[N]=E
__global__ __launch_bounds__(256) void k_scan(const int* __restrict__ hist,
                                              int* __restrict__ row_start,
                                              int* __restrict__ cursor) {
    __shared__ int buf[256];
    __shared__ int carry_s;
    if (threadIdx.x == 0) carry_s = 0;
    __syncthreads();
    for (int base = 0; base < N_NODES; base += 256) {
        int i = base + threadIdx.x;
        int v = (i < N_NODES) ? hist[i] : 0;
        buf[threadIdx.x] = v;
        __syncthreads();
        for (int off = 1; off < 256; off <<= 1) {
            int t = (threadIdx.x >= off) ? buf[threadIdx.x - off] : 0;
            __syncthreads();
            buf[threadIdx.x] += t;
            __syncthreads();
        }
        int excl = carry_s + buf[threadIdx.x] - v;
        if (i < N_NODES) { row_start[i] = excl; cursor[i] = excl; }
        __syncthreads();
        if (threadIdx.x == 255) carry_s += buf[255];
        __syncthreads();
    }
    if (threadIdx.x == 0) row_start[N_NODES] = carry_s;
}

__global__ __launch_bounds__(256) void k_scatter(const int* __restrict__ src,
                                                 const int* __restrict__ dst,
                                                 const float* __restrict__ dis,
                                                 int* __restrict__ cursor,
                                                 int* __restrict__ csrc,
                                                 float* __restrict__ csrw) {
    int e = blockIdx.x * 256 + threadIdx.x;
    if (e >= N_EDGES) return;
    int s = src[e], d = dst[e];
    int pos = atomicAdd(&cursor[d], 1);
    csrc[pos] = s;
    csrw[pos] = dis[s] * dis[d];
}

// ---------------- embedding GEMM: h = x @ emb_w.T + emb_b ----------------
// block: 64 rows x 64 cols (blockIdx.y selects col half), thread: 4x4

__global__ __launch_bounds__(256) void k_embed(const float* __restrict__ x,
                                               const float* __restrict__ emb_w,
                                               const float* __restrict__ emb_b,
                                               float* __restrict__ out) {
    __shared__ __align__(16) float xs[64 * 65];   // [row][k], pad 65
    __shared__ __align__(16) float wt[64 * 68];   // [k][col], pad 68
    int rowbase = blockIdx.x * 64;
    int cbase   = blockIdx.y * 64;
    int tid = threadIdx.x;
    for (int i = tid; i < 64 * 64; i += 256) {
        int r = i >> 6, k = i & 63;
        int row = rowbase + r;
        xs[r * 65 + k] = (row < N_NODES) ? x[row * F_INDIM + k] : 0.f;
        wt[k * 68 + r] = emb_w[(cbase + r) * F_INDIM + k];  // r doubles as local col
    }
    __syncthreads();
    int cg = tid & 15, rg = tid >> 4;
    int c0 = cg * 4;
    float acc[4][4] = {};
#pragma unroll 4
    for (int k = 0; k < 64; ++k) {
        float4 w = *(float4*)&wt[k * 68 + c0];
#pragma unroll
        for (int i = 0; i < 4; ++i) {
            float hv = xs[(rg * 4 + i) * 65 + k];
            acc[i][0] += hv * w.x; acc[i][1] += hv * w.y;
            acc[i][2] += hv * w.z; acc[i][3] += hv * w.w;
        }
    }
    float4 eb = *(const float4*)&emb_b[cbase + c0];
#pragma unroll
    for (int i = 0; i < 4; ++i) {
        int row = rowbase + rg * 4 + i;
        if (row < N_NODES) {
            float4 o = make_float4(acc[i][0] + eb.x, acc[i][1] + eb.y,
                                   acc[i][2] + eb.z, acc[i][3] + eb.w);
            *(float4*)&out[row * HDIM + cbase + c0] = o;
        }
    }
}

// ---------------- GCN GEMM: hw = h @ W.T (no bias) ----------------
// block: 64 rows x 64 cols; k=128 staged in two 64-slices (LDS ~50KB -> 3 blk/CU)

__global__ __launch_bounds__(256) void k_gemm(const float* __restrict__ A,
                                              const float* __restrict__ W,
                                              float* __restrict__ B) {
    __shared__ __align__(16) float hs[64 * 129];  // [row][k] pad 129, 33KB
    __shared__ __align__(16) float wt[64 * 68];   // [kk][col] pad 68, 17.4KB
    int rowbase = blockIdx.x * 64;
    int cbase   = blockIdx.y * 64;
    int tid = threadIdx.x;
    for (int i = tid; i < 64 * 128; i += 256) {
        int r = i >> 7, k = i & 127;
        int row = rowbase + r;
        hs[r * 129 + k] = (row < N_NODES) ? A[row * HDIM + k] : 0.f;
    }
    int cg = tid & 15, rg = tid >> 4;
    int c0 = cg * 4;
    float acc[4][4] = {};
    for (int kb = 0; kb < 2; ++kb) {
        __syncthreads();  // protect wt overwrite; also covers hs readiness on kb=0
        for (int i = tid; i < 64 * 64; i += 256) {
            int cl = i >> 6, kk = i & 63;
            wt[kk * 68 + cl] = W[(cbase + cl) * HDIM + kb * 64 + kk];
        }
        __syncthreads();
#pragma unroll 4
        for (int kk = 0; kk < 64; ++kk) {
            int k = kb * 64 + kk;
            float4 w = *(float4*)&wt[kk * 68 + c0];
#pragma unroll
            for (int i = 0; i < 4; ++i) {
                float hv = hs[(rg * 4 + i) * 129 + k];
                acc[i][0] += hv * w.x; acc[i][1] += hv * w.y;
                acc[i][2] += hv * w.z; acc[i][3] += hv * w.w;
            }
        }
    }
#pragma unroll
    for (int i = 0; i < 4; ++i) {
        int row = rowbase + rg * 4 + i;
        if (row < N_NODES) {
            *(float4*)&B[row * HDIM + cbase + c0] =
                make_float4(acc[i][0], acc[i][1], acc[i][2], acc[i][3]);
        }
    }
}

// ---------------- GCN aggregation (gather over CSR) + self + bias + relu ----------------
// one wave per node, lane = channel (c and c+64)

__global__ __launch_bounds__(256) void k_gather(const float* __restrict__ hw,
                                                const int* __restrict__ row_start,
                                                const int* __restrict__ csrc,
                                                const float* __restrict__ csrw,
                                                const float* __restrict__ dis,
                                                const float* __restrict__ bias,
                                                float* __restrict__ hout) {
    int n = blockIdx.x * 4 + (threadIdx.x >> 6);
    int lane = threadIdx.x & 63;
    if (n >= N_NODES) return;
    int beg = row_start[n], end = row_start[n + 1];
    float acc0 = 0.f, acc1 = 0.f;
    for (int e = beg; e < end; ++e) {
        int s = csrc[e];
        float w = csrw[e];
        acc0 += w * hw[s * HDIM + lane];
        acc1 += w * hw[s * HDIM + 64 + lane];
    }
    float dn = dis[n];
    float sn = dn * dn;
    acc0 += sn * hw[n * HDIM + lane];
    acc1 += sn * hw[n * HDIM + 64 + lane];
    acc0 += bias[lane];
    acc1 += bias[64 + lane];
    hout[n * HDIM + lane]      = fmaxf(acc0, 0.f);
    hout[n * HDIM + 64 + lane] = fmaxf(acc1, 0.f);
}

// ---------------- mean-pool accumulation (run-length, batch_idx sorted) ----------------

#define POOL_CHUNK 512
__global__ __launch_bounds__(256) void k_pool(const float* __restrict__ h,
                                              const int* __restrict__ batch,
                                              float* __restrict__ pool,
                                              float* __restrict__ counts) {
    int base = blockIdx.x * POOL_CHUNK;
    int c = threadIdx.x & 127;
    int half = threadIdx.x >> 7;
    float acc = 0.f, cnt = 0.f;
    int cur = -1;
    for (int i = half; i < POOL_CHUNK; i += 2) {
        int n = base + i;
        if (n >= N_NODES) break;
        int g = batch[n];
        if (g != cur) {
            if (cur >= 0) {
                atomicAdd(&pool[cur * HDIM + c], acc);
                if (c == 0) atomicAdd(&counts[cur], cnt);
            }
            cur = g; acc = 0.f; cnt = 0.f;
        }
        acc += h[n * HDIM + c];
        cnt += 1.f;
    }
    if (cur >= 0) {
        atomicAdd(&pool[cur * HDIM + c], acc);
        if (c == 0) atomicAdd(&counts[cur], cnt);
    }
}

// ---------------- tail: mean -> LSTM(seq=1) -> attn(v passthrough) -> MLP ----------------
// one block per graph, 128 threads

__global__ __launch_bounds__(128) void k_tail(const float* __restrict__ pool,
                                              const float* __restrict__ counts,
                                              const float* __restrict__ w_ih,
                                              const float* __restrict__ b_ih,
                                              const float* __restrict__ b_hh,
                                              const float* __restrict__ attn_in_w,
                                              const float* __restrict__ attn_in_b,
                                              const float* __restrict__ attn_out_w,
                                              const float* __restrict__ attn_out_b,
                                              const float* __restrict__ w1,
                                              const float* __restrict__ b1,
                                              const float* __restrict__ w2,
                                              const float* __restrict__ b2,
                                              float* __restrict__ out) {
    __shared__ float ge[128], hsr[128], vv[128], fe[128], zz[64];
    int g = blockIdx.x, t = threadIdx.x;
    float cnt = fmaxf(counts[g], 1.0f);
    ge[t] = pool[g * HDIM + t] / cnt;
    __syncthreads();
    // gates (i, g, o rows; f unused since c0=0)
    float gi = 0.f, gg = 0.f, go = 0.f;
    for (int k = 0; k < 128; ++k) {
        float xv = ge[k];
        gi += xv * w_ih[t * HDIM + k];
        gg += xv * w_ih[(256 + t) * HDIM + k];
        go += xv * w_ih[(384 + t) * HDIM + k];
    }
    gi += b_ih[t] + b_hh[t];
    gg += b_ih[256 + t] + b_hh[256 + t];
    go += b_ih[384 + t] + b_hh[384 + t];
    float cc = (1.f / (1.f + expf(-gi))) * tanhf(gg);
    float hv = (1.f / (1.f + expf(-go))) * tanhf(cc);
    hsr[t] = hv;
    __syncthreads();
    // attention with S=1: softmax == 1 -> ctx == v; q,k dead
    float va = attn_in_b[256 + t];
    for (int k = 0; k < 128; ++k) va += hsr[k] * attn_in_w[(256 + t) * HDIM + k];
    vv[t] = va;
    __syncthreads();
    float fv = attn_out_b[t];
    for (int k = 0; k < 128; ++k) fv += vv[k] * attn_out_w[t * HDIM + k];
    fe[t] = fv;
    __syncthreads();
    if (t < 64) {
        float zv = b1[t];
        for (int k = 0; k < 128; ++k) zv += fe[k] * w1[t * HDIM + k];
        zz[t] = fmaxf(zv, 0.f);
    }
    __syncthreads();
    if (t < NCLS) {
        float ov = b2[t];
        for (int k = 0; k < 64; ++k) ov += zz[k] * w2[t * 64 + k];
        out[g * NCLS + t] = ov;
    }
}

// ---------------- launch ----------------

extern "C" void kernel_launch(void* const* d_in, const int* in_sizes, int n_in,
                              void* d_out, int out_size, void* d_ws, size_t ws_size,
                              hipStream_t stream) {
    const float* x          = (const float*)d_in[0];
    const int*   edge_index = (const int*)d_in[1];
    const int*   batch      = (const int*)d_in[2];
    const float* emb_w      = (const float*)d_in[3];
    const float* emb_b      = (const float*)d_in[4];
    const float* gcn_w      = (const float*)d_in[5];
    const float* gcn_b      = (const float*)d_in[6];
    const float* w_ih       = (const float*)d_in[7];
    // d_in[8] = lstm_w_hh (unused: h0 = 0)
    const float* b_ih       = (const float*)d_in[9];
    const float* b_hh       = (const float*)d_in[10];
    const float* attn_in_w  = (const float*)d_in[11];
    const float* attn_in_b  = (const float*)d_in[12];
    const float* attn_out_w = (const float*)d_in[13];
    const float* attn_out_b = (const float*)d_in[14];
    const float* w1         = (const float*)d_in[15];
    const float* b1         = (const float*)d_in[16];
    const float* w2         = (const float*)d_in[17];
    const float* b2         = (const float*)d_in[18];
    float* out = (float*)d_out;

    // workspace layout (elements). total ~14.29M * 4B = 57.2MB
    int*   iws = (int*)d_ws;
    float* fws = (float*)d_ws;
    int*   hist      = iws;
    float* dis       = fws + N_NODES;
    int*   row_start = iws + 2 * N_NODES;          // N+1
    int*   cursor    = iws + 3 * N_NODES + 4;
    int*   csrc      = iws + 4 * N_NODES + 8;
    float* csrw      = fws + 4 * N_NODES + 8 + N_EDGES;
    float* bufA      = fws + 4 * N_NODES + 8 + 2 * N_EDGES;   // 16B aligned
    float* bufB      = bufA + (size_t)N_NODES * HDIM;
    float* pool      = bufB + (size_t)N_NODES * HDIM;
    float* counts    = pool + NGRAPH * HDIM;

    const int* src = edge_index;
    const int* dst = edge_index + N_EDGES;

    k_init<<<196, 256, 0, stream>>>(hist, pool, counts);
    k_hist<<<(N_EDGES + 255) / 256, 256, 0, stream>>>(dst, hist);
    k_dis<<<196, 256, 0, stream>>>(hist, dis);
    k_scan<<<1, 256, 0, stream>>>(hist, row_start, cursor);
    k_scatter<<<(N_EDGES + 255) / 256, 256, 0, stream>>>(src, dst, dis, cursor, csrc, csrw);

    dim3 ggrid((N_NODES + 63) / 64, 2);
    k_embed<<<ggrid, 256, 0, stream>>>(x, emb_w, emb_b, bufA);
    for (int l = 0; l < NLAYERS; ++l) {
        k_gemm<<<ggrid, 256, 0, stream>>>(bufA, gcn_w + l * HDIM * HDIM, bufB);
        k_gather<<<(N_NODES + 3) / 4, 256, 0, stream>>>(bufB, row_start, csrc, csrw, dis,
                                                        gcn_b + l * HDIM, bufA);
    }
    k_pool<<<(N_NODES + POOL_CHUNK - 1) / POOL_CHUNK, 256, 0, stream>>>(bufA, batch, pool, counts);
    k_tail<<<NGRAPH, 128, 0, stream>>>(pool, counts, w_ih, b_ih, b_hh,
                                       attn_in_w, attn_in_b, attn_out_w, attn_out_b,
                                       w1, b1, w2, b2, out);
}

// Round 2
// 684.189 us; speedup vs baseline: 1.3002x; 1.3002x over previous
//
#include <hip/hip_runtime.h>
#include <math.h>

#define N_NODES 50000
#define N_EDGES 640000
#define F_INDIM 64
#define HDIM 128
#define NLAYERS 3
#define NGRAPH 64
#define NCLS 2
#define SCAN_BLOCKS ((N_NODES + 255) / 256)   // 196

// ---------------- init / degree / CSR build ----------------

__global__ __launch_bounds__(256) void k_init(int* hist, float* pool, float* counts) {
    int i = blockIdx.x * 256 + threadIdx.x;
    if (i < N_NODES) hist[i] = 0;
    if (i < NGRAPH * HDIM) pool[i] = 0.f;
    if (i < NGRAPH) counts[i] = 0.f;
}

__global__ __launch_bounds__(256) void k_hist(const int* __restrict__ dst, int* __restrict__ hist) {
    int e = blockIdx.x * 256 + threadIdx.x;
    if (e < N_EDGES) atomicAdd(&hist[dst[e]], 1);
}

// phase 1: per-block inclusive scan of hist; writes per-element exclusive (block-local)
// into row_start, block total into partials. Also computes dis = rsqrt(deg+1).
__global__ __launch_bounds__(256) void k_scan1(const int* __restrict__ hist,
                                               int* __restrict__ row_start,
                                               int* __restrict__ partials,
                                               float* __restrict__ dis) {
    __shared__ int buf[256];
    int i = blockIdx.x * 256 + threadIdx.x;
    int v = (i < N_NODES) ? hist[i] : 0;
    if (i < N_NODES) dis[i] = rsqrtf((float)v + 1.0f);
    buf[threadIdx.x] = v;
    __syncthreads();
#pragma unroll
    for (int off = 1; off < 256; off <<= 1) {
        int t = (threadIdx.x >= off) ? buf[threadIdx.x - off] : 0;
        __syncthreads();
        buf[threadIdx.x] += t;
        __syncthreads();
    }
    if (i < N_NODES) row_start[i] = buf[threadIdx.x] - v;   // block-local exclusive
    if (threadIdx.x == 255) partials[blockIdx.x] = buf[255];
}

// phase 2: single block scans the 196 partials (exclusive, in place)
__global__ __launch_bounds__(256) void k_scan2(int* __restrict__ partials) {
    __shared__ int buf[256];
    int v = (threadIdx.x < SCAN_BLOCKS) ? partials[threadIdx.x] : 0;
    buf[threadIdx.x] = v;
    __syncthreads();
#pragma unroll
    for (int off = 1; off < 256; off <<= 1) {
        int t = (threadIdx.x >= off) ? buf[threadIdx.x - off] : 0;
        __syncthreads();
        buf[threadIdx.x] += t;
        __syncthreads();
    }
    if (threadIdx.x < SCAN_BLOCKS) partials[threadIdx.x] = buf[threadIdx.x] - v;
}

// phase 3: add block offsets; produce final row_start and cursor copy.
// row_start[N_NODES] = N_EDGES (every edge has a dst) — constant.
__global__ __launch_bounds__(256) void k_scan3(int* __restrict__ row_start,
                                               const int* __restrict__ partials,
                                               int* __restrict__ cursor) {
    int i = blockIdx.x * 256 + threadIdx.x;
    if (i < N_NODES) {
        int r = row_start[i] + partials[blockIdx.x];
        row_start[i] = r;
        cursor[i] = r;
    }
    if (i == 0) row_start[N_NODES] = N_EDGES;
}

__global__ __launch_bounds__(256) void k_scatter(const int* __restrict__ src,
                                                 const int* __restrict__ dst,
                                                 const float* __restrict__ dis,
                                                 int* __restrict__ cursor,
                                                 int* __restrict__ csrc,
                                                 float* __restrict__ csrw) {
    int e = blockIdx.x * 256 + threadIdx.x;
    if (e >= N_EDGES) return;
    int s = src[e], d = dst[e];
    int pos = atomicAdd(&cursor[d], 1);
    csrc[pos] = s;
    csrw[pos] = dis[s] * dis[d];
}

// ---------------- embedding GEMM: h = x @ emb_w.T + emb_b ----------------
// block: 64 rows x 64 cols (blockIdx.y selects col half), thread: 4x4

__global__ __launch_bounds__(256) void k_embed(const float* __restrict__ x,
                                               const float* __restrict__ emb_w,
                                               const float* __restrict__ emb_b,
                                               float* __restrict__ out) {
    __shared__ __align__(16) float xs[64 * 65];   // [row][k], pad 65
    __shared__ __align__(16) float wt[64 * 68];   // [k][col], pad 68
    int rowbase = blockIdx.x * 64;
    int cbase   = blockIdx.y * 64;
    int tid = threadIdx.x;
    for (int i = tid; i < 64 * 64; i += 256) {
        int r = i >> 6, k = i & 63;
        int row = rowbase + r;
        xs[r * 65 + k] = (row < N_NODES) ? x[row * F_INDIM + k] : 0.f;
        wt[k * 68 + r] = emb_w[(cbase + r) * F_INDIM + k];  // r doubles as local col
    }
    __syncthreads();
    int cg = tid & 15, rg = tid >> 4;
    int c0 = cg * 4;
    float acc[4][4] = {};
#pragma unroll 4
    for (int k = 0; k < 64; ++k) {
        float4 w = *(float4*)&wt[k * 68 + c0];
#pragma unroll
        for (int i = 0; i < 4; ++i) {
            float hv = xs[(rg * 4 + i) * 65 + k];
            acc[i][0] += hv * w.x; acc[i][1] += hv * w.y;
            acc[i][2] += hv * w.z; acc[i][3] += hv * w.w;
        }
    }
    float4 eb = *(const float4*)&emb_b[cbase + c0];
#pragma unroll
    for (int i = 0; i < 4; ++i) {
        int row = rowbase + rg * 4 + i;
        if (row < N_NODES) {
            float4 o = make_float4(acc[i][0] + eb.x, acc[i][1] + eb.y,
                                   acc[i][2] + eb.z, acc[i][3] + eb.w);
            *(float4*)&out[row * HDIM + cbase + c0] = o;
        }
    }
}

// ---------------- GCN GEMM: hw = h @ W.T (no bias) ----------------
// block: 64 rows x 64 cols; k=128 staged in two 64-slices (LDS ~50KB -> 3 blk/CU)

__global__ __launch_bounds__(256) void k_gemm(const float* __restrict__ A,
                                              const float* __restrict__ W,
                                              float* __restrict__ B) {
    __shared__ __align__(16) float hs[64 * 129];  // [row][k] pad 129, 33KB
    __shared__ __align__(16) float wt[64 * 68];   // [kk][col] pad 68, 17.4KB
    int rowbase = blockIdx.x * 64;
    int cbase   = blockIdx.y * 64;
    int tid = threadIdx.x;
    for (int i = tid; i < 64 * 128; i += 256) {
        int r = i >> 7, k = i & 127;
        int row = rowbase + r;
        hs[r * 129 + k] = (row < N_NODES) ? A[row * HDIM + k] : 0.f;
    }
    int cg = tid & 15, rg = tid >> 4;
    int c0 = cg * 4;
    float acc[4][4] = {};
    for (int kb = 0; kb < 2; ++kb) {
        __syncthreads();  // protect wt overwrite; also covers hs readiness on kb=0
        for (int i = tid; i < 64 * 64; i += 256) {
            int cl = i >> 6, kk = i & 63;
            wt[kk * 68 + cl] = W[(cbase + cl) * HDIM + kb * 64 + kk];
        }
        __syncthreads();
#pragma unroll 4
        for (int kk = 0; kk < 64; ++kk) {
            int k = kb * 64 + kk;
            float4 w = *(float4*)&wt[kk * 68 + c0];
#pragma unroll
            for (int i = 0; i < 4; ++i) {
                float hv = hs[(rg * 4 + i) * 129 + k];
                acc[i][0] += hv * w.x; acc[i][1] += hv * w.y;
                acc[i][2] += hv * w.z; acc[i][3] += hv * w.w;
            }
        }
    }
#pragma unroll
    for (int i = 0; i < 4; ++i) {
        int row = rowbase + rg * 4 + i;
        if (row < N_NODES) {
            *(float4*)&B[row * HDIM + cbase + c0] =
                make_float4(acc[i][0], acc[i][1], acc[i][2], acc[i][3]);
        }
    }
}

// ---------------- GCN aggregation (gather over CSR) + self + bias + relu ----------------
// one wave per node, lane = channel (c and c+64)

__global__ __launch_bounds__(256) void k_gather(const float* __restrict__ hw,
                                                const int* __restrict__ row_start,
                                                const int* __restrict__ csrc,
                                                const float* __restrict__ csrw,
                                                const float* __restrict__ dis,
                                                const float* __restrict__ bias,
                                                float* __restrict__ hout) {
    int n = blockIdx.x * 4 + (threadIdx.x >> 6);
    int lane = threadIdx.x & 63;
    if (n >= N_NODES) return;
    int beg = row_start[n], end = row_start[n + 1];
    float acc0 = 0.f, acc1 = 0.f;
    for (int e = beg; e < end; ++e) {
        int s = csrc[e];
        float w = csrw[e];
        acc0 += w * hw[s * HDIM + lane];
        acc1 += w * hw[s * HDIM + 64 + lane];
    }
    float dn = dis[n];
    float sn = dn * dn;
    acc0 += sn * hw[n * HDIM + lane];
    acc1 += sn * hw[n * HDIM + 64 + lane];
    acc0 += bias[lane];
    acc1 += bias[64 + lane];
    hout[n * HDIM + lane]      = fmaxf(acc0, 0.f);
    hout[n * HDIM + 64 + lane] = fmaxf(acc1, 0.f);
}

// ---------------- mean-pool accumulation (run-length, batch_idx sorted) ----------------

#define POOL_CHUNK 512
__global__ __launch_bounds__(256) void k_pool(const float* __restrict__ h,
                                              const int* __restrict__ batch,
                                              float* __restrict__ pool,
                                              float* __restrict__ counts) {
    int base = blockIdx.x * POOL_CHUNK;
    int c = threadIdx.x & 127;
    int half = threadIdx.x >> 7;
    float acc = 0.f, cnt = 0.f;
    int cur = -1;
    for (int i = half; i < POOL_CHUNK; i += 2) {
        int n = base + i;
        if (n >= N_NODES) break;
        int g = batch[n];
        if (g != cur) {
            if (cur >= 0) {
                atomicAdd(&pool[cur * HDIM + c], acc);
                if (c == 0) atomicAdd(&counts[cur], cnt);
            }
            cur = g; acc = 0.f; cnt = 0.f;
        }
        acc += h[n * HDIM + c];
        cnt += 1.f;
    }
    if (cur >= 0) {
        atomicAdd(&pool[cur * HDIM + c], acc);
        if (c == 0) atomicAdd(&counts[cur], cnt);
    }
}

// ---------------- tail: mean -> LSTM(seq=1) -> attn(v passthrough) -> MLP ----------------
// one block per graph, 128 threads

__global__ __launch_bounds__(128) void k_tail(const float* __restrict__ pool,
                                              const float* __restrict__ counts,
                                              const float* __restrict__ w_ih,
                                              const float* __restrict__ b_ih,
                                              const float* __restrict__ b_hh,
                                              const float* __restrict__ attn_in_w,
                                              const float* __restrict__ attn_in_b,
                                              const float* __restrict__ attn_out_w,
                                              const float* __restrict__ attn_out_b,
                                              const float* __restrict__ w1,
                                              const float* __restrict__ b1,
                                              const float* __restrict__ w2,
                                              const float* __restrict__ b2,
                                              float* __restrict__ out) {
    __shared__ float ge[128], hsr[128], vv[128], fe[128], zz[64];
    int g = blockIdx.x, t = threadIdx.x;
    float cnt = fmaxf(counts[g], 1.0f);
    ge[t] = pool[g * HDIM + t] / cnt;
    __syncthreads();
    // gates (i, g, o rows; f unused since c0=0)
    float gi = 0.f, gg = 0.f, go = 0.f;
    for (int k = 0; k < 128; ++k) {
        float xv = ge[k];
        gi += xv * w_ih[t * HDIM + k];
        gg += xv * w_ih[(256 + t) * HDIM + k];
        go += xv * w_ih[(384 + t) * HDIM + k];
    }
    gi += b_ih[t] + b_hh[t];
    gg += b_ih[256 + t] + b_hh[256 + t];
    go += b_ih[384 + t] + b_hh[384 + t];
    float cc = (1.f / (1.f + expf(-gi))) * tanhf(gg);
    float hv = (1.f / (1.f + expf(-go))) * tanhf(cc);
    hsr[t] = hv;
    __syncthreads();
    // attention with S=1: softmax == 1 -> ctx == v; q,k dead
    float va = attn_in_b[256 + t];
    for (int k = 0; k < 128; ++k) va += hsr[k] * attn_in_w[(256 + t) * HDIM + k];
    vv[t] = va;
    __syncthreads();
    float fv = attn_out_b[t];
    for (int k = 0; k < 128; ++k) fv += vv[k] * attn_out_w[t * HDIM + k];
    fe[t] = fv;
    __syncthreads();
    if (t < 64) {
        float zv = b1[t];
        for (int k = 0; k < 128; ++k) zv += fe[k] * w1[t * HDIM + k];
        zz[t] = fmaxf(zv, 0.f);
    }
    __syncthreads();
    if (t < NCLS) {
        float ov = b2[t];
        for (int k = 0; k < 64; ++k) ov += zz[k] * w2[t * 64 + k];
        out[g * NCLS + t] = ov;
    }
}

// ---------------- launch ----------------

extern "C" void kernel_launch(void* const* d_in, const int* in_sizes, int n_in,
                              void* d_out, int out_size, void* d_ws, size_t ws_size,
                              hipStream_t stream) {
    const float* x          = (const float*)d_in[0];
    const int*   edge_index = (const int*)d_in[1];
    const int*   batch      = (const int*)d_in[2];
    const float* emb_w      = (const float*)d_in[3];
    const float* emb_b      = (const float*)d_in[4];
    const float* gcn_w      = (const float*)d_in[5];
    const float* gcn_b      = (const float*)d_in[6];
    const float* w_ih       = (const float*)d_in[7];
    // d_in[8] = lstm_w_hh (unused: h0 = 0)
    const float* b_ih       = (const float*)d_in[9];
    const float* b_hh       = (const float*)d_in[10];
    const float* attn_in_w  = (const float*)d_in[11];
    const float* attn_in_b  = (const float*)d_in[12];
    const float* attn_out_w = (const float*)d_in[13];
    const float* attn_out_b = (const float*)d_in[14];
    const float* w1         = (const float*)d_in[15];
    const float* b1         = (const float*)d_in[16];
    const float* w2         = (const float*)d_in[17];
    const float* b2         = (const float*)d_in[18];
    float* out = (float*)d_out;

    // workspace layout (elements). total ~14.3M * 4B = 57.2MB
    int*   iws = (int*)d_ws;
    float* fws = (float*)d_ws;
    int*   hist      = iws;
    float* dis       = fws + N_NODES;
    int*   row_start = iws + 2 * N_NODES;          // N+1
    int*   cursor    = iws + 3 * N_NODES + 4;
    int*   csrc      = iws + 4 * N_NODES + 8;
    float* csrw      = fws + 4 * N_NODES + 8 + N_EDGES;
    float* bufA      = fws + 4 * N_NODES + 8 + 2 * N_EDGES;   // 16B aligned
    float* bufB      = bufA + (size_t)N_NODES * HDIM;
    float* pool      = bufB + (size_t)N_NODES * HDIM;
    float* counts    = pool + NGRAPH * HDIM;
    int*   partials  = (int*)(counts + NGRAPH);    // SCAN_BLOCKS ints

    const int* src = edge_index;
    const int* dst = edge_index + N_EDGES;

    k_init<<<196, 256, 0, stream>>>(hist, pool, counts);
    k_hist<<<(N_EDGES + 255) / 256, 256, 0, stream>>>(dst, hist);
    k_scan1<<<SCAN_BLOCKS, 256, 0, stream>>>(hist, row_start, partials, dis);
    k_scan2<<<1, 256, 0, stream>>>(partials);
    k_scan3<<<SCAN_BLOCKS, 256, 0, stream>>>(row_start, partials, cursor);
    k_scatter<<<(N_EDGES + 255) / 256, 256, 0, stream>>>(src, dst, dis, cursor, csrc, csrw);

    dim3 ggrid((N_NODES + 63) / 64, 2);
    k_embed<<<ggrid, 256, 0, stream>>>(x, emb_w, emb_b, bufA);
    for (int l = 0; l < NLAYERS; ++l) {
        k_gemm<<<ggrid, 256, 0, stream>>>(bufA, gcn_w + l * HDIM * HDIM, bufB);
        k_gather<<<(N_NODES + 3) / 4, 256, 0, stream>>>(bufB, row_start, csrc, csrw, dis,
                                                        gcn_b + l * HDIM, bufA);
    }
    k_pool<<<(N_NODES + POOL_CHUNK - 1) / POOL_CHUNK, 256, 0, stream>>>(bufA, batch, pool, counts);
    k_tail<<<NGRAPH, 128, 0, stream>>>(pool, counts, w_ih, b_ih, b_hh,
                                       attn_in_w, attn_in_b, attn_out_w, attn_out_b,
                                       w1, b1, w2, b2, out);
}

// Round 3
// 561.535 us; speedup vs baseline: 1.5841x; 1.2184x over previous
//
#include <hip/hip_runtime.h>
#include <math.h>

#define N_NODES 50000
#define N_EDGES 640000
#define F_INDIM 64
#define HDIM 128
#define NLAYERS 3
#define NGRAPH 64
#define NCLS 2
#define SCAN_BLOCKS ((N_NODES + 255) / 256)   // 196
#define POOL_SPLIT 8

// ---------------- init / degree / CSR build ----------------

__global__ __launch_bounds__(256) void k_init(int* hist, float* pool, float* counts) {
    int i = blockIdx.x * 256 + threadIdx.x;
    if (i < N_NODES) hist[i] = 0;
    if (i < NGRAPH * HDIM) pool[i] = 0.f;
    if (i < NGRAPH) counts[i] = 0.f;
}

__global__ __launch_bounds__(256) void k_hist(const int* __restrict__ dst, int* __restrict__ hist) {
    int e = blockIdx.x * 256 + threadIdx.x;
    if (e < N_EDGES) atomicAdd(&hist[dst[e]], 1);
}

// phase 1: per-block inclusive scan of hist; writes per-element exclusive (block-local)
// into row_start, block total into partials. Also computes dis = rsqrt(deg+1).
__global__ __launch_bounds__(256) void k_scan1(const int* __restrict__ hist,
                                               int* __restrict__ row_start,
                                               int* __restrict__ partials,
                                               float* __restrict__ dis) {
    __shared__ int buf[256];
    int i = blockIdx.x * 256 + threadIdx.x;
    int v = (i < N_NODES) ? hist[i] : 0;
    if (i < N_NODES) dis[i] = rsqrtf((float)v + 1.0f);
    buf[threadIdx.x] = v;
    __syncthreads();
#pragma unroll
    for (int off = 1; off < 256; off <<= 1) {
        int t = (threadIdx.x >= off) ? buf[threadIdx.x - off] : 0;
        __syncthreads();
        buf[threadIdx.x] += t;
        __syncthreads();
    }
    if (i < N_NODES) row_start[i] = buf[threadIdx.x] - v;   // block-local exclusive
    if (threadIdx.x == 255) partials[blockIdx.x] = buf[255];
}

// phase 2: single block scans the 196 partials (exclusive, in place)
__global__ __launch_bounds__(256) void k_scan2(int* __restrict__ partials) {
    __shared__ int buf[256];
    int v = (threadIdx.x < SCAN_BLOCKS) ? partials[threadIdx.x] : 0;
    buf[threadIdx.x] = v;
    __syncthreads();
#pragma unroll
    for (int off = 1; off < 256; off <<= 1) {
        int t = (threadIdx.x >= off) ? buf[threadIdx.x - off] : 0;
        __syncthreads();
        buf[threadIdx.x] += t;
        __syncthreads();
    }
    if (threadIdx.x < SCAN_BLOCKS) partials[threadIdx.x] = buf[threadIdx.x] - v;
}

// phase 3: add block offsets; produce final row_start and cursor copy.
__global__ __launch_bounds__(256) void k_scan3(int* __restrict__ row_start,
                                               const int* __restrict__ partials,
                                               int* __restrict__ cursor) {
    int i = blockIdx.x * 256 + threadIdx.x;
    if (i < N_NODES) {
        int r = row_start[i] + partials[blockIdx.x];
        row_start[i] = r;
        cursor[i] = r;
    }
    if (i == 0) row_start[N_NODES] = N_EDGES;
}

__global__ __launch_bounds__(256) void k_scatter(const int* __restrict__ src,
                                                 const int* __restrict__ dst,
                                                 const float* __restrict__ dis,
                                                 int* __restrict__ cursor,
                                                 int* __restrict__ csrc,
                                                 float* __restrict__ csrw) {
    int e = blockIdx.x * 256 + threadIdx.x;
    if (e >= N_EDGES) return;
    int s = src[e], d = dst[e];
    int pos = atomicAdd(&cursor[d], 1);
    csrc[pos] = s;
    csrw[pos] = dis[s] * dis[d];
}

// ---------------- embedding GEMM: h = x @ emb_w.T + emb_b ----------------

__global__ __launch_bounds__(256) void k_embed(const float* __restrict__ x,
                                               const float* __restrict__ emb_w,
                                               const float* __restrict__ emb_b,
                                               float* __restrict__ out) {
    __shared__ __align__(16) float xs[64 * 65];   // [row][k], pad 65
    __shared__ __align__(16) float wt[64 * 68];   // [k][col], pad 68
    int rowbase = blockIdx.x * 64;
    int cbase   = blockIdx.y * 64;
    int tid = threadIdx.x;
    for (int i = tid; i < 64 * 64; i += 256) {
        int r = i >> 6, k = i & 63;
        int row = rowbase + r;
        xs[r * 65 + k] = (row < N_NODES) ? x[row * F_INDIM + k] : 0.f;
        wt[k * 68 + r] = emb_w[(cbase + r) * F_INDIM + k];  // r doubles as local col
    }
    __syncthreads();
    int cg = tid & 15, rg = tid >> 4;
    int c0 = cg * 4;
    float acc[4][4] = {};
#pragma unroll 4
    for (int k = 0; k < 64; ++k) {
        float4 w = *(float4*)&wt[k * 68 + c0];
#pragma unroll
        for (int i = 0; i < 4; ++i) {
            float hv = xs[(rg * 4 + i) * 65 + k];
            acc[i][0] += hv * w.x; acc[i][1] += hv * w.y;
            acc[i][2] += hv * w.z; acc[i][3] += hv * w.w;
        }
    }
    float4 eb = *(const float4*)&emb_b[cbase + c0];
#pragma unroll
    for (int i = 0; i < 4; ++i) {
        int row = rowbase + rg * 4 + i;
        if (row < N_NODES) {
            float4 o = make_float4(acc[i][0] + eb.x, acc[i][1] + eb.y,
                                   acc[i][2] + eb.z, acc[i][3] + eb.w);
            *(float4*)&out[row * HDIM + cbase + c0] = o;
        }
    }
}

// ---------------- GCN GEMM: hw = h @ W.T (no bias) ----------------

__global__ __launch_bounds__(256) void k_gemm(const float* __restrict__ A,
                                              const float* __restrict__ W,
                                              float* __restrict__ B) {
    __shared__ __align__(16) float hs[64 * 129];  // [row][k] pad 129, 33KB
    __shared__ __align__(16) float wt[64 * 68];   // [kk][col] pad 68, 17.4KB
    int rowbase = blockIdx.x * 64;
    int cbase   = blockIdx.y * 64;
    int tid = threadIdx.x;
    for (int i = tid; i < 64 * 128; i += 256) {
        int r = i >> 7, k = i & 127;
        int row = rowbase + r;
        hs[r * 129 + k] = (row < N_NODES) ? A[row * HDIM + k] : 0.f;
    }
    int cg = tid & 15, rg = tid >> 4;
    int c0 = cg * 4;
    float acc[4][4] = {};
    for (int kb = 0; kb < 2; ++kb) {
        __syncthreads();
        for (int i = tid; i < 64 * 64; i += 256) {
            int cl = i >> 6, kk = i & 63;
            wt[kk * 68 + cl] = W[(cbase + cl) * HDIM + kb * 64 + kk];
        }
        __syncthreads();
#pragma unroll 4
        for (int kk = 0; kk < 64; ++kk) {
            int k = kb * 64 + kk;
            float4 w = *(float4*)&wt[kk * 68 + c0];
#pragma unroll
            for (int i = 0; i < 4; ++i) {
                float hv = hs[(rg * 4 + i) * 129 + k];
                acc[i][0] += hv * w.x; acc[i][1] += hv * w.y;
                acc[i][2] += hv * w.z; acc[i][3] += hv * w.w;
            }
        }
    }
#pragma unroll
    for (int i = 0; i < 4; ++i) {
        int row = rowbase + rg * 4 + i;
        if (row < N_NODES) {
            *(float4*)&B[row * HDIM + cbase + c0] =
                make_float4(acc[i][0], acc[i][1], acc[i][2], acc[i][3]);
        }
    }
}

// ---------------- GCN aggregation (gather over CSR) + self + bias + relu ----------------

__global__ __launch_bounds__(256) void k_gather(const float* __restrict__ hw,
                                                const int* __restrict__ row_start,
                                                const int* __restrict__ csrc,
                                                const float* __restrict__ csrw,
                                                const float* __restrict__ dis,
                                                const float* __restrict__ bias,
                                                float* __restrict__ hout) {
    int n = blockIdx.x * 4 + (threadIdx.x >> 6);
    int lane = threadIdx.x & 63;
    if (n >= N_NODES) return;
    int beg = row_start[n], end = row_start[n + 1];
    float acc0 = 0.f, acc1 = 0.f;
    for (int e = beg; e < end; ++e) {
        int s = csrc[e];
        float w = csrw[e];
        acc0 += w * hw[s * HDIM + lane];
        acc1 += w * hw[s * HDIM + 64 + lane];
    }
    float dn = dis[n];
    float sn = dn * dn;
    acc0 += sn * hw[n * HDIM + lane];
    acc1 += sn * hw[n * HDIM + 64 + lane];
    acc0 += bias[lane];
    acc1 += bias[64 + lane];
    hout[n * HDIM + lane]      = fmaxf(acc0, 0.f);
    hout[n * HDIM + 64 + lane] = fmaxf(acc1, 0.f);
}

// ---------------- mean-pool: 64 graphs x 8 slices, binary-search boundaries ----------------

__global__ __launch_bounds__(256) void k_pool(const float* __restrict__ h,
                                              const int* __restrict__ batch,
                                              float* __restrict__ pool,
                                              float* __restrict__ counts) {
    int g  = blockIdx.x >> 3;   // graph
    int sp = blockIdx.x & 7;    // slice
    // lower_bound: first index with batch[i] >= val
    int s, e;
    {
        int lo = 0, hi = N_NODES;
        while (lo < hi) { int mid = (lo + hi) >> 1; if (batch[mid] < g) lo = mid + 1; else hi = mid; }
        s = lo;
        lo = s; hi = N_NODES;
        while (lo < hi) { int mid = (lo + hi) >> 1; if (batch[mid] < g + 1) lo = mid + 1; else hi = mid; }
        e = lo;
    }
    int len = e - s;
    int chunk = (len + POOL_SPLIT - 1) / POOL_SPLIT;
    int ss = s + sp * chunk;
    int ee = min(ss + chunk, e);
    int cg = threadIdx.x & 31;  // channel group (4 floats)
    int r  = threadIdx.x >> 5;  // 8 rows
    float4 acc = make_float4(0.f, 0.f, 0.f, 0.f);
    for (int n = ss + r; n < ee; n += 8) {
        float4 v = *(const float4*)&h[(size_t)n * HDIM + cg * 4];
        acc.x += v.x; acc.y += v.y; acc.z += v.z; acc.w += v.w;
    }
    __shared__ float4 red[8][32];
    red[r][cg] = acc;
    __syncthreads();
    if (r == 0) {
        float4 a = red[0][cg];
#pragma unroll
        for (int j = 1; j < 8; ++j) {
            float4 b = red[j][cg];
            a.x += b.x; a.y += b.y; a.z += b.z; a.w += b.w;
        }
        atomicAdd(&pool[g * HDIM + cg * 4 + 0], a.x);
        atomicAdd(&pool[g * HDIM + cg * 4 + 1], a.y);
        atomicAdd(&pool[g * HDIM + cg * 4 + 2], a.z);
        atomicAdd(&pool[g * HDIM + cg * 4 + 3], a.w);
    }
    if (threadIdx.x == 0 && ee > ss) atomicAdd(&counts[g], (float)(ee - ss));
}

// ---------------- tail: mean -> LSTM(seq=1) -> attn(v passthrough) -> MLP ----------------

__global__ __launch_bounds__(128) void k_tail(const float* __restrict__ pool,
                                              const float* __restrict__ counts,
                                              const float* __restrict__ w_ih,
                                              const float* __restrict__ b_ih,
                                              const float* __restrict__ b_hh,
                                              const float* __restrict__ attn_in_w,
                                              const float* __restrict__ attn_in_b,
                                              const float* __restrict__ attn_out_w,
                                              const float* __restrict__ attn_out_b,
                                              const float* __restrict__ w1,
                                              const float* __restrict__ b1,
                                              const float* __restrict__ w2,
                                              const float* __restrict__ b2,
                                              float* __restrict__ out) {
    __shared__ float ge[128], hsr[128], vv[128], fe[128], zz[64];
    int g = blockIdx.x, t = threadIdx.x;
    float cnt = fmaxf(counts[g], 1.0f);
    ge[t] = pool[g * HDIM + t] / cnt;
    __syncthreads();
    float gi = 0.f, gg = 0.f, go = 0.f;
    for (int k = 0; k < 128; ++k) {
        float xv = ge[k];
        gi += xv * w_ih[t * HDIM + k];
        gg += xv * w_ih[(256 + t) * HDIM + k];
        go += xv * w_ih[(384 + t) * HDIM + k];
    }
    gi += b_ih[t] + b_hh[t];
    gg += b_ih[256 + t] + b_hh[256 + t];
    go += b_ih[384 + t] + b_hh[384 + t];
    float cc = (1.f / (1.f + expf(-gi))) * tanhf(gg);
    float hv = (1.f / (1.f + expf(-go))) * tanhf(cc);
    hsr[t] = hv;
    __syncthreads();
    float va = attn_in_b[256 + t];
    for (int k = 0; k < 128; ++k) va += hsr[k] * attn_in_w[(256 + t) * HDIM + k];
    vv[t] = va;
    __syncthreads();
    float fv = attn_out_b[t];
    for (int k = 0; k < 128; ++k) fv += vv[k] * attn_out_w[t * HDIM + k];
    fe[t] = fv;
    __syncthreads();
    if (t < 64) {
        float zv = b1[t];
        for (int k = 0; k < 128; ++k) zv += fe[k] * w1[t * HDIM + k];
        zz[t] = fmaxf(zv, 0.f);
    }
    __syncthreads();
    if (t < NCLS) {
        float ov = b2[t];
        for (int k = 0; k < 64; ++k) ov += zz[k] * w2[t * 64 + k];
        out[g * NCLS + t] = ov;
    }
}

// ---------------- launch ----------------

extern "C" void kernel_launch(void* const* d_in, const int* in_sizes, int n_in,
                              void* d_out, int out_size, void* d_ws, size_t ws_size,
                              hipStream_t stream) {
    const float* x          = (const float*)d_in[0];
    const int*   edge_index = (const int*)d_in[1];
    const int*   batch      = (const int*)d_in[2];
    const float* emb_w      = (const float*)d_in[3];
    const float* emb_b      = (const float*)d_in[4];
    const float* gcn_w      = (const float*)d_in[5];
    const float* gcn_b      = (const float*)d_in[6];
    const float* w_ih       = (const float*)d_in[7];
    // d_in[8] = lstm_w_hh (unused: h0 = 0)
    const float* b_ih       = (const float*)d_in[9];
    const float* b_hh       = (const float*)d_in[10];
    const float* attn_in_w  = (const float*)d_in[11];
    const float* attn_in_b  = (const float*)d_in[12];
    const float* attn_out_w = (const float*)d_in[13];
    const float* attn_out_b = (const float*)d_in[14];
    const float* w1         = (const float*)d_in[15];
    const float* b1         = (const float*)d_in[16];
    const float* w2         = (const float*)d_in[17];
    const float* b2         = (const float*)d_in[18];
    float* out = (float*)d_out;

    int*   iws = (int*)d_ws;
    float* fws = (float*)d_ws;
    int*   hist      = iws;
    float* dis       = fws + N_NODES;
    int*   row_start = iws + 2 * N_NODES;          // N+1
    int*   cursor    = iws + 3 * N_NODES + 4;
    int*   csrc      = iws + 4 * N_NODES + 8;
    float* csrw      = fws + 4 * N_NODES + 8 + N_EDGES;
    float* bufA      = fws + 4 * N_NODES + 8 + 2 * N_EDGES;   // 16B aligned
    float* bufB      = bufA + (size_t)N_NODES * HDIM;
    float* pool      = bufB + (size_t)N_NODES * HDIM;
    float* counts    = pool + NGRAPH * HDIM;
    int*   partials  = (int*)(counts + NGRAPH);    // SCAN_BLOCKS ints

    const int* src = edge_index;
    const int* dst = edge_index + N_EDGES;

    k_init<<<196, 256, 0, stream>>>(hist, pool, counts);
    k_hist<<<(N_EDGES + 255) / 256, 256, 0, stream>>>(dst, hist);
    k_scan1<<<SCAN_BLOCKS, 256, 0, stream>>>(hist, row_start, partials, dis);
    k_scan2<<<1, 256, 0, stream>>>(partials);
    k_scan3<<<SCAN_BLOCKS, 256, 0, stream>>>(row_start, partials, cursor);
    k_scatter<<<(N_EDGES + 255) / 256, 256, 0, stream>>>(src, dst, dis, cursor, csrc, csrw);

    dim3 ggrid((N_NODES + 63) / 64, 2);
    k_embed<<<ggrid, 256, 0, stream>>>(x, emb_w, emb_b, bufA);
    for (int l = 0; l < NLAYERS; ++l) {
        k_gemm<<<ggrid, 256, 0, stream>>>(bufA, gcn_w + l * HDIM * HDIM, bufB);
        k_gather<<<(N_NODES + 3) / 4, 256, 0, stream>>>(bufB, row_start, csrc, csrw, dis,
                                                        gcn_b + l * HDIM, bufA);
    }
    k_pool<<<NGRAPH * POOL_SPLIT, 256, 0, stream>>>(bufA, batch, pool, counts);
    k_tail<<<NGRAPH, 128, 0, stream>>>(pool, counts, w_ih, b_ih, b_hh,
                                       attn_in_w, attn_in_b, attn_out_w, attn_out_b,
                                       w1, b1, w2, b2, out);
}

// Round 4
// 391.998 us; speedup vs baseline: 2.2693x; 1.4325x over previous
//
#include <hip/hip_runtime.h>
#include <math.h>

#define N_NODES 50000
#define N_EDGES 640000
#define F_INDIM 64
#define HDIM 128
#define NLAYERS 3
#define NGRAPH 64
#define NCLS 2
#define SCAN_BLOCKS ((N_NODES + 255) / 256)   // 196
#define POOL_SPLIT 8
#define NTILES (N_NODES / 16)                 // 3125 row-tiles (exact)

typedef __attribute__((ext_vector_type(8))) short bf16x8;   // 8 bf16 (4 VGPRs)
typedef __attribute__((ext_vector_type(4))) float f32x4;

__device__ __forceinline__ float bf_lo(unsigned v) { return __uint_as_float(v << 16); }
__device__ __forceinline__ float bf_hi(unsigned v) { return __uint_as_float(v & 0xffff0000u); }
__device__ __forceinline__ unsigned short f2bf(float f) {
    unsigned b = __float_as_uint(f);
    return (unsigned short)((b + 0x7fffu + ((b >> 16) & 1u)) >> 16);   // RNE
}

// ---------------- init / degree / CSR build ----------------

__global__ __launch_bounds__(256) void k_init(int* hist, float* pool, float* counts) {
    int i = blockIdx.x * 256 + threadIdx.x;
    if (i < N_NODES) hist[i] = 0;
    if (i < NGRAPH * HDIM) pool[i] = 0.f;
    if (i < NGRAPH) counts[i] = 0.f;
}

__global__ __launch_bounds__(256) void k_hist(const int* __restrict__ dst, int* __restrict__ hist) {
    int e = blockIdx.x * 256 + threadIdx.x;
    if (e < N_EDGES) atomicAdd(&hist[dst[e]], 1);
}

__global__ __launch_bounds__(256) void k_scan1(const int* __restrict__ hist,
                                               int* __restrict__ row_start,
                                               int* __restrict__ partials,
                                               float* __restrict__ dis) {
    __shared__ int buf[256];
    int i = blockIdx.x * 256 + threadIdx.x;
    int v = (i < N_NODES) ? hist[i] : 0;
    if (i < N_NODES) dis[i] = rsqrtf((float)v + 1.0f);
    buf[threadIdx.x] = v;
    __syncthreads();
#pragma unroll
    for (int off = 1; off < 256; off <<= 1) {
        int t = (threadIdx.x >= off) ? buf[threadIdx.x - off] : 0;
        __syncthreads();
        buf[threadIdx.x] += t;
        __syncthreads();
    }
    if (i < N_NODES) row_start[i] = buf[threadIdx.x] - v;
    if (threadIdx.x == 255) partials[blockIdx.x] = buf[255];
}

__global__ __launch_bounds__(256) void k_scan2(int* __restrict__ partials) {
    __shared__ int buf[256];
    int v = (threadIdx.x < SCAN_BLOCKS) ? partials[threadIdx.x] : 0;
    buf[threadIdx.x] = v;
    __syncthreads();
#pragma unroll
    for (int off = 1; off < 256; off <<= 1) {
        int t = (threadIdx.x >= off) ? buf[threadIdx.x - off] : 0;
        __syncthreads();
        buf[threadIdx.x] += t;
        __syncthreads();
    }
    if (threadIdx.x < SCAN_BLOCKS) partials[threadIdx.x] = buf[threadIdx.x] - v;
}

__global__ __launch_bounds__(256) void k_scan3(int* __restrict__ row_start,
                                               const int* __restrict__ partials,
                                               int* __restrict__ cursor) {
    int i = blockIdx.x * 256 + threadIdx.x;
    if (i < N_NODES) {
        int r = row_start[i] + partials[blockIdx.x];
        row_start[i] = r;
        cursor[i] = r;
    }
    if (i == 0) row_start[N_NODES] = N_EDGES;
}

__global__ __launch_bounds__(256) void k_scatter(const int* __restrict__ src,
                                                 const int* __restrict__ dst,
                                                 const float* __restrict__ dis,
                                                 int* __restrict__ cursor,
                                                 int* __restrict__ csrc,
                                                 float* __restrict__ csrw) {
    int e = blockIdx.x * 256 + threadIdx.x;
    if (e >= N_EDGES) return;
    int s = src[e], d = dst[e];
    int pos = atomicAdd(&cursor[d], 1);
    csrc[pos] = s;
    csrw[pos] = dis[s] * dis[d];
}

// ---------------- fp32 -> bf16 conversion (4 elems/thread) ----------------

__global__ __launch_bounds__(256) void k_cvt(const float* __restrict__ src,
                                             unsigned short* __restrict__ dst, int n4) {
    int i = blockIdx.x * 256 + threadIdx.x;
    if (i >= n4) return;
    float4 v = *(const float4*)&src[i * 4];
    unsigned r0 = (unsigned)f2bf(v.x) | ((unsigned)f2bf(v.y) << 16);
    unsigned r1 = (unsigned)f2bf(v.z) | ((unsigned)f2bf(v.w) << 16);
    *(uint2*)&dst[i * 4] = make_uint2(r0, r1);
}

// ---------------- MFMA GEMM: C[M,128] = A[M,K](bf16) @ W[128,K](bf16)^T (+bias) ----------------
// 256 thr = 4 waves; wave w owns cols [32w, 32w+32); block owns 4 row-tiles of 16.
// A-frag: lane holds A[rb + (l&15)][ks*32 + (l>>4)*8 + 0..7]; W-frag same pattern on W rows.
// C/D: col = l&15, row = (l>>4)*4 + j  [m89-verified].

template<int K>
__global__ __launch_bounds__(256) void k_mm(const unsigned short* __restrict__ A,
                                            const unsigned short* __restrict__ W,
                                            const float* __restrict__ bias,
                                            unsigned short* __restrict__ C) {
    constexpr int KS = K / 32;
    int lane = threadIdx.x & 63;
    int lg = lane >> 4, lr = lane & 15;
    int cb = (threadIdx.x >> 6) * 32;          // wave col base
    int tile0 = blockIdx.x * 4;

    bf16x8 wf[2][KS];
#pragma unroll
    for (int ct = 0; ct < 2; ++ct)
#pragma unroll
        for (int ks = 0; ks < KS; ++ks)
            wf[ct][ks] = *(const bf16x8*)&W[(size_t)(cb + ct * 16 + lr) * K + ks * 32 + lg * 8];

    float b0 = bias ? bias[cb + lr] : 0.f;
    float b1 = bias ? bias[cb + 16 + lr] : 0.f;

    int ntile = NTILES - tile0; if (ntile > 4) ntile = 4;
    for (int t = 0; t < ntile; ++t) {
        int rb = (tile0 + t) * 16;
        f32x4 acc0 = {0.f, 0.f, 0.f, 0.f}, acc1 = {0.f, 0.f, 0.f, 0.f};
#pragma unroll
        for (int ks = 0; ks < KS; ++ks) {
            bf16x8 af = *(const bf16x8*)&A[(size_t)(rb + lr) * K + ks * 32 + lg * 8];
            acc0 = __builtin_amdgcn_mfma_f32_16x16x32_bf16(af, wf[0][ks], acc0, 0, 0, 0);
            acc1 = __builtin_amdgcn_mfma_f32_16x16x32_bf16(af, wf[1][ks], acc1, 0, 0, 0);
        }
        int row = rb + lg * 4;
#pragma unroll
        for (int j = 0; j < 4; ++j) {
            C[(size_t)(row + j) * HDIM + cb + lr]      = f2bf(acc0[j] + b0);
            C[(size_t)(row + j) * HDIM + cb + 16 + lr] = f2bf(acc1[j] + b1);
        }
    }
}

// ---------------- GCN aggregation (gather over CSR, bf16 in/out) ----------------
// wave per node; lane owns channel pair (2*lane, 2*lane+1)

__global__ __launch_bounds__(256) void k_gather(const unsigned short* __restrict__ hw,
                                                const int* __restrict__ row_start,
                                                const int* __restrict__ csrc,
                                                const float* __restrict__ csrw,
                                                const float* __restrict__ dis,
                                                const float* __restrict__ bias,
                                                unsigned short* __restrict__ hout) {
    int n = blockIdx.x * 4 + (threadIdx.x >> 6);
    int lane = threadIdx.x & 63;
    if (n >= N_NODES) return;
    int beg = row_start[n], end = row_start[n + 1];
    float a0 = 0.f, a1 = 0.f;
    for (int e = beg; e < end; ++e) {
        int s = csrc[e];
        float w = csrw[e];
        unsigned v = *(const unsigned*)&hw[(size_t)s * HDIM + lane * 2];
        a0 += w * bf_lo(v);
        a1 += w * bf_hi(v);
    }
    float dn = dis[n];
    float sn = dn * dn;
    unsigned vs = *(const unsigned*)&hw[(size_t)n * HDIM + lane * 2];
    a0 += sn * bf_lo(vs);
    a1 += sn * bf_hi(vs);
    a0 = fmaxf(a0 + bias[lane * 2], 0.f);
    a1 = fmaxf(a1 + bias[lane * 2 + 1], 0.f);
    unsigned r = (unsigned)f2bf(a0) | ((unsigned)f2bf(a1) << 16);
    *(unsigned*)&hout[(size_t)n * HDIM + lane * 2] = r;
}

// ---------------- mean-pool: 64 graphs x 8 slices, bf16 input ----------------

__global__ __launch_bounds__(256) void k_pool(const unsigned short* __restrict__ h,
                                              const int* __restrict__ batch,
                                              float* __restrict__ pool,
                                              float* __restrict__ counts) {
    int g  = blockIdx.x >> 3;
    int sp = blockIdx.x & 7;
    int s, e;
    {
        int lo = 0, hi = N_NODES;
        while (lo < hi) { int mid = (lo + hi) >> 1; if (batch[mid] < g) lo = mid + 1; else hi = mid; }
        s = lo;
        lo = s; hi = N_NODES;
        while (lo < hi) { int mid = (lo + hi) >> 1; if (batch[mid] < g + 1) lo = mid + 1; else hi = mid; }
        e = lo;
    }
    int len = e - s;
    int chunk = (len + POOL_SPLIT - 1) / POOL_SPLIT;
    int ss = s + sp * chunk;
    int ee = min(ss + chunk, e);
    int cp = threadIdx.x & 63;   // channel pair
    int r  = threadIdx.x >> 6;   // 4 rows
    float a0 = 0.f, a1 = 0.f;
    for (int n = ss + r; n < ee; n += 4) {
        unsigned v = *(const unsigned*)&h[(size_t)n * HDIM + cp * 2];
        a0 += bf_lo(v);
        a1 += bf_hi(v);
    }
    __shared__ float red0[4][64], red1[4][64];
    red0[r][cp] = a0; red1[r][cp] = a1;
    __syncthreads();
    if (r == 0) {
#pragma unroll
        for (int j = 1; j < 4; ++j) { a0 += red0[j][cp]; a1 += red1[j][cp]; }
        atomicAdd(&pool[g * HDIM + cp * 2], a0);
        atomicAdd(&pool[g * HDIM + cp * 2 + 1], a1);
    }
    if (threadIdx.x == 0 && ee > ss) atomicAdd(&counts[g], (float)(ee - ss));
}

// ---------------- tail: mean -> LSTM(seq=1) -> attn(v passthrough) -> MLP ----------------

__global__ __launch_bounds__(128) void k_tail(const float* __restrict__ pool,
                                              const float* __restrict__ counts,
                                              const float* __restrict__ w_ih,
                                              const float* __restrict__ b_ih,
                                              const float* __restrict__ b_hh,
                                              const float* __restrict__ attn_in_w,
                                              const float* __restrict__ attn_in_b,
                                              const float* __restrict__ attn_out_w,
                                              const float* __restrict__ attn_out_b,
                                              const float* __restrict__ w1,
                                              const float* __restrict__ b1,
                                              const float* __restrict__ w2,
                                              const float* __restrict__ b2,
                                              float* __restrict__ out) {
    __shared__ float ge[128], hsr[128], vv[128], fe[128], zz[64];
    int g = blockIdx.x, t = threadIdx.x;
    float cnt = fmaxf(counts[g], 1.0f);
    ge[t] = pool[g * HDIM + t] / cnt;
    __syncthreads();
    float gi = 0.f, gg = 0.f, go = 0.f;
    for (int k = 0; k < 128; ++k) {
        float xv = ge[k];
        gi += xv * w_ih[t * HDIM + k];
        gg += xv * w_ih[(256 + t) * HDIM + k];
        go += xv * w_ih[(384 + t) * HDIM + k];
    }
    gi += b_ih[t] + b_hh[t];
    gg += b_ih[256 + t] + b_hh[256 + t];
    go += b_ih[384 + t] + b_hh[384 + t];
    float cc = (1.f / (1.f + expf(-gi))) * tanhf(gg);
    float hv = (1.f / (1.f + expf(-go))) * tanhf(cc);
    hsr[t] = hv;
    __syncthreads();
    float va = attn_in_b[256 + t];
    for (int k = 0; k < 128; ++k) va += hsr[k] * attn_in_w[(256 + t) * HDIM + k];
    vv[t] = va;
    __syncthreads();
    float fv = attn_out_b[t];
    for (int k = 0; k < 128; ++k) fv += vv[k] * attn_out_w[t * HDIM + k];
    fe[t] = fv;
    __syncthreads();
    if (t < 64) {
        float zv = b1[t];
        for (int k = 0; k < 128; ++k) zv += fe[k] * w1[t * HDIM + k];
        zz[t] = fmaxf(zv, 0.f);
    }
    __syncthreads();
    if (t < NCLS) {
        float ov = b2[t];
        for (int k = 0; k < 64; ++k) ov += zz[k] * w2[t * 64 + k];
        out[g * NCLS + t] = ov;
    }
}

// ---------------- launch ----------------

extern "C" void kernel_launch(void* const* d_in, const int* in_sizes, int n_in,
                              void* d_out, int out_size, void* d_ws, size_t ws_size,
                              hipStream_t stream) {
    const float* x          = (const float*)d_in[0];
    const int*   edge_index = (const int*)d_in[1];
    const int*   batch      = (const int*)d_in[2];
    const float* emb_w      = (const float*)d_in[3];
    const float* emb_b      = (const float*)d_in[4];
    const float* gcn_w      = (const float*)d_in[5];
    const float* gcn_b      = (const float*)d_in[6];
    const float* w_ih       = (const float*)d_in[7];
    // d_in[8] = lstm_w_hh (unused: h0 = 0)
    const float* b_ih       = (const float*)d_in[9];
    const float* b_hh       = (const float*)d_in[10];
    const float* attn_in_w  = (const float*)d_in[11];
    const float* attn_in_b  = (const float*)d_in[12];
    const float* attn_out_w = (const float*)d_in[13];
    const float* attn_out_b = (const float*)d_in[14];
    const float* w1         = (const float*)d_in[15];
    const float* b1         = (const float*)d_in[16];
    const float* w2         = (const float*)d_in[17];
    const float* b2         = (const float*)d_in[18];
    float* out = (float*)d_out;

    // ---- workspace layout ----
    int*   iws = (int*)d_ws;
    float* fws = (float*)d_ws;
    int*   hist      = iws;                         // N
    float* dis       = fws + N_NODES;               // N
    int*   row_start = iws + 2 * N_NODES;           // N+1
    int*   cursor    = iws + 3 * N_NODES + 4;       // N
    int*   csrc      = iws + 4 * N_NODES + 8;       // E
    float* csrw      = fws + 4 * N_NODES + 8 + N_EDGES;  // E
    // bf16 region (16B-aligned: word offset 1480008 -> byte 5920032, %16==0)
    unsigned short* bws   = (unsigned short*)(iws + 4 * N_NODES + 8 + 2 * N_EDGES);
    unsigned short* x_bf  = bws;                                    // N*64
    unsigned short* we_bf = x_bf + (size_t)N_NODES * F_INDIM;       // 128*64
    unsigned short* wg_bf = we_bf + HDIM * F_INDIM;                 // 3*128*128
    unsigned short* hA    = wg_bf + NLAYERS * HDIM * HDIM;          // N*128
    unsigned short* hB    = hA + (size_t)N_NODES * HDIM;            // N*128
    float* pool     = (float*)(hB + (size_t)N_NODES * HDIM);        // 64*128
    float* counts   = pool + NGRAPH * HDIM;                         // 64
    int*   partials = (int*)(counts + NGRAPH);                      // SCAN_BLOCKS

    const int* src = edge_index;
    const int* dst = edge_index + N_EDGES;

    k_init<<<196, 256, 0, stream>>>(hist, pool, counts);
    k_hist<<<(N_EDGES + 255) / 256, 256, 0, stream>>>(dst, hist);
    k_scan1<<<SCAN_BLOCKS, 256, 0, stream>>>(hist, row_start, partials, dis);
    k_scan2<<<1, 256, 0, stream>>>(partials);
    k_scan3<<<SCAN_BLOCKS, 256, 0, stream>>>(row_start, partials, cursor);
    k_scatter<<<(N_EDGES + 255) / 256, 256, 0, stream>>>(src, dst, dis, cursor, csrc, csrw);

    // conversions
    k_cvt<<<(N_NODES * F_INDIM / 4 + 255) / 256, 256, 0, stream>>>(x, x_bf, N_NODES * F_INDIM / 4);
    k_cvt<<<(HDIM * F_INDIM / 4 + 255) / 256, 256, 0, stream>>>(emb_w, we_bf, HDIM * F_INDIM / 4);
    k_cvt<<<(NLAYERS * HDIM * HDIM / 4 + 255) / 256, 256, 0, stream>>>(gcn_w, wg_bf, NLAYERS * HDIM * HDIM / 4);

    int mm_grid = (NTILES + 3) / 4;   // 782
    k_mm<F_INDIM><<<mm_grid, 256, 0, stream>>>(x_bf, we_bf, emb_b, hA);
    for (int l = 0; l < NLAYERS; ++l) {
        k_mm<HDIM><<<mm_grid, 256, 0, stream>>>(hA, wg_bf + l * HDIM * HDIM, nullptr, hB);
        k_gather<<<N_NODES / 4, 256, 0, stream>>>(hB, row_start, csrc, csrw, dis,
                                                  gcn_b + l * HDIM, hA);
    }
    k_pool<<<NGRAPH * POOL_SPLIT, 256, 0, stream>>>(hA, batch, pool, counts);
    k_tail<<<NGRAPH, 128, 0, stream>>>(pool, counts, w_ih, b_ih, b_hh,
                                       attn_in_w, attn_in_b, attn_out_w, attn_out_b,
                                       w1, b1, w2, b2, out);
}

// Round 5
// 288.696 us; speedup vs baseline: 3.0813x; 1.3578x over previous
//
#include <hip/hip_runtime.h>
#include <math.h>

#define N_NODES 50000
#define N_EDGES 640000
#define F_INDIM 64
#define HDIM 128
#define NLAYERS 3
#define NGRAPH 64
#define NCLS 2
#define SCAN_BLOCKS ((N_NODES + 255) / 256)   // 196
#define POOL_SPLIT 8
#define NTILES (N_NODES / 16)                 // 3125 row-tiles (exact)

typedef __attribute__((ext_vector_type(8))) short bf16x8;   // 8 bf16 (4 VGPRs)
typedef __attribute__((ext_vector_type(4))) float f32x4;

__device__ __forceinline__ float bf_lo(unsigned v) { return __uint_as_float(v << 16); }
__device__ __forceinline__ float bf_hi(unsigned v) { return __uint_as_float(v & 0xffff0000u); }
__device__ __forceinline__ unsigned short f2bf(float f) {
    unsigned b = __float_as_uint(f);
    return (unsigned short)((b + 0x7fffu + ((b >> 16) & 1u)) >> 16);   // RNE
}

// ---------------- init / degree / CSR build ----------------

__global__ __launch_bounds__(256) void k_init(int* hist, float* pool, float* counts) {
    int i = blockIdx.x * 256 + threadIdx.x;
    if (i < N_NODES) hist[i] = 0;
    if (i < NGRAPH * HDIM) pool[i] = 0.f;
    if (i < NGRAPH) counts[i] = 0.f;
}

__global__ __launch_bounds__(256) void k_hist(const int* __restrict__ dst, int* __restrict__ hist) {
    int e = blockIdx.x * 256 + threadIdx.x;
    if (e < N_EDGES) atomicAdd(&hist[dst[e]], 1);
}

__global__ __launch_bounds__(256) void k_scan1(const int* __restrict__ hist,
                                               int* __restrict__ row_start,
                                               int* __restrict__ partials,
                                               float* __restrict__ dis) {
    __shared__ int buf[256];
    int i = blockIdx.x * 256 + threadIdx.x;
    int v = (i < N_NODES) ? hist[i] : 0;
    if (i < N_NODES) dis[i] = rsqrtf((float)v + 1.0f);
    buf[threadIdx.x] = v;
    __syncthreads();
#pragma unroll
    for (int off = 1; off < 256; off <<= 1) {
        int t = (threadIdx.x >= off) ? buf[threadIdx.x - off] : 0;
        __syncthreads();
        buf[threadIdx.x] += t;
        __syncthreads();
    }
    if (i < N_NODES) row_start[i] = buf[threadIdx.x] - v;
    if (threadIdx.x == 255) partials[blockIdx.x] = buf[255];
}

__global__ __launch_bounds__(256) void k_scan2(int* __restrict__ partials) {
    __shared__ int buf[256];
    int v = (threadIdx.x < SCAN_BLOCKS) ? partials[threadIdx.x] : 0;
    buf[threadIdx.x] = v;
    __syncthreads();
#pragma unroll
    for (int off = 1; off < 256; off <<= 1) {
        int t = (threadIdx.x >= off) ? buf[threadIdx.x - off] : 0;
        __syncthreads();
        buf[threadIdx.x] += t;
        __syncthreads();
    }
    if (threadIdx.x < SCAN_BLOCKS) partials[threadIdx.x] = buf[threadIdx.x] - v;
}

__global__ __launch_bounds__(256) void k_scan3(int* __restrict__ row_start,
                                               const int* __restrict__ partials,
                                               int* __restrict__ cursor) {
    int i = blockIdx.x * 256 + threadIdx.x;
    if (i < N_NODES) {
        int r = row_start[i] + partials[blockIdx.x];
        row_start[i] = r;
        cursor[i] = r;
    }
    if (i == 0) row_start[N_NODES] = N_EDGES;
}

__global__ __launch_bounds__(256) void k_scatter(const int* __restrict__ src,
                                                 const int* __restrict__ dst,
                                                 const float* __restrict__ dis,
                                                 int* __restrict__ cursor,
                                                 int* __restrict__ csrc,
                                                 float* __restrict__ csrw) {
    int e = blockIdx.x * 256 + threadIdx.x;
    if (e >= N_EDGES) return;
    int s = src[e], d = dst[e];
    int pos = atomicAdd(&cursor[d], 1);
    csrc[pos] = s;
    csrw[pos] = dis[s] * dis[d];
}

// ---------------- fp32 -> bf16 conversion (4 elems/thread) ----------------

__global__ __launch_bounds__(256) void k_cvt(const float* __restrict__ src,
                                             unsigned short* __restrict__ dst, int n4) {
    int i = blockIdx.x * 256 + threadIdx.x;
    if (i >= n4) return;
    float4 v = *(const float4*)&src[i * 4];
    unsigned r0 = (unsigned)f2bf(v.x) | ((unsigned)f2bf(v.y) << 16);
    unsigned r1 = (unsigned)f2bf(v.z) | ((unsigned)f2bf(v.w) << 16);
    *(uint2*)&dst[i * 4] = make_uint2(r0, r1);
}

// ---------------- MFMA GEMM: C[M,128] = A[M,K](bf16) @ W[128,K](bf16)^T (+bias) ----------------

template<int K>
__global__ __launch_bounds__(256) void k_mm(const unsigned short* __restrict__ A,
                                            const unsigned short* __restrict__ W,
                                            const float* __restrict__ bias,
                                            unsigned short* __restrict__ C) {
    constexpr int KS = K / 32;
    int lane = threadIdx.x & 63;
    int lg = lane >> 4, lr = lane & 15;
    int cb = (threadIdx.x >> 6) * 32;          // wave col base
    int tile0 = blockIdx.x * 4;

    bf16x8 wf[2][KS];
#pragma unroll
    for (int ct = 0; ct < 2; ++ct)
#pragma unroll
        for (int ks = 0; ks < KS; ++ks)
            wf[ct][ks] = *(const bf16x8*)&W[(size_t)(cb + ct * 16 + lr) * K + ks * 32 + lg * 8];

    float b0 = bias ? bias[cb + lr] : 0.f;
    float b1 = bias ? bias[cb + 16 + lr] : 0.f;

    int ntile = NTILES - tile0; if (ntile > 4) ntile = 4;
    for (int t = 0; t < ntile; ++t) {
        int rb = (tile0 + t) * 16;
        f32x4 acc0 = {0.f, 0.f, 0.f, 0.f}, acc1 = {0.f, 0.f, 0.f, 0.f};
#pragma unroll
        for (int ks = 0; ks < KS; ++ks) {
            bf16x8 af = *(const bf16x8*)&A[(size_t)(rb + lr) * K + ks * 32 + lg * 8];
            acc0 = __builtin_amdgcn_mfma_f32_16x16x32_bf16(af, wf[0][ks], acc0, 0, 0, 0);
            acc1 = __builtin_amdgcn_mfma_f32_16x16x32_bf16(af, wf[1][ks], acc1, 0, 0, 0);
        }
        int row = rb + lg * 4;
#pragma unroll
        for (int j = 0; j < 4; ++j) {
            C[(size_t)(row + j) * HDIM + cb + lr]      = f2bf(acc0[j] + b0);
            C[(size_t)(row + j) * HDIM + cb + 16 + lr] = f2bf(acc1[j] + b1);
        }
    }
}

// ---------------- GCN aggregation (gather over CSR, bf16 in/out) ----------------
// wave per node; lanes 0-31 = even edges, lanes 32-63 = odd edges;
// each lane owns a channel quad (4 channels, 8B loads). 4-pair unroll -> 8 edges in flight.

__global__ __launch_bounds__(256) void k_gather(const unsigned short* __restrict__ hw,
                                                const int* __restrict__ row_start,
                                                const int* __restrict__ csrc,
                                                const float* __restrict__ csrw,
                                                const float* __restrict__ dis,
                                                const float* __restrict__ bias,
                                                unsigned short* __restrict__ hout) {
    int n = blockIdx.x * 4 + (threadIdx.x >> 6);
    int lane = threadIdx.x & 63;
    int half = lane >> 5;
    int cl = lane & 31;              // channel quad: channels 4*cl .. 4*cl+3
    int beg = row_start[n], end = row_start[n + 1];
    float a0 = 0.f, a1 = 0.f, a2 = 0.f, a3 = 0.f;
    int e = beg;
    for (; e + 8 <= end; e += 8) {
        int s[4]; float w[4]; uint2 v[4];
#pragma unroll
        for (int u = 0; u < 4; ++u) {
            int me = e + 2 * u + half;
            s[u] = csrc[me];
            w[u] = csrw[me];
        }
#pragma unroll
        for (int u = 0; u < 4; ++u)
            v[u] = *(const uint2*)&hw[(size_t)s[u] * HDIM + cl * 4];
#pragma unroll
        for (int u = 0; u < 4; ++u) {
            a0 += w[u] * bf_lo(v[u].x);
            a1 += w[u] * bf_hi(v[u].x);
            a2 += w[u] * bf_lo(v[u].y);
            a3 += w[u] * bf_hi(v[u].y);
        }
    }
    for (; e < end; e += 2) {
        int me = e + half;
        bool valid = me < end;
        int s = valid ? csrc[me] : n;
        float w = valid ? csrw[me] : 0.f;
        uint2 v = *(const uint2*)&hw[(size_t)s * HDIM + cl * 4];
        a0 += w * bf_lo(v.x); a1 += w * bf_hi(v.x);
        a2 += w * bf_lo(v.y); a3 += w * bf_hi(v.y);
    }
    // cross-half combine (even-edge partial + odd-edge partial)
    a0 += __shfl_xor(a0, 32); a1 += __shfl_xor(a1, 32);
    a2 += __shfl_xor(a2, 32); a3 += __shfl_xor(a3, 32);
    if (half == 0) {
        float dn = dis[n], sn = dn * dn;
        uint2 vs = *(const uint2*)&hw[(size_t)n * HDIM + cl * 4];
        a0 += sn * bf_lo(vs.x); a1 += sn * bf_hi(vs.x);
        a2 += sn * bf_lo(vs.y); a3 += sn * bf_hi(vs.y);
        float4 b = *(const float4*)&bias[cl * 4];
        a0 = fmaxf(a0 + b.x, 0.f); a1 = fmaxf(a1 + b.y, 0.f);
        a2 = fmaxf(a2 + b.z, 0.f); a3 = fmaxf(a3 + b.w, 0.f);
        uint2 r;
        r.x = (unsigned)f2bf(a0) | ((unsigned)f2bf(a1) << 16);
        r.y = (unsigned)f2bf(a2) | ((unsigned)f2bf(a3) << 16);
        *(uint2*)&hout[(size_t)n * HDIM + cl * 4] = r;
    }
}

// ---------------- mean-pool: 64 graphs x 8 slices, bf16 input ----------------

__global__ __launch_bounds__(256) void k_pool(const unsigned short* __restrict__ h,
                                              const int* __restrict__ batch,
                                              float* __restrict__ pool,
                                              float* __restrict__ counts) {
    int g  = blockIdx.x >> 3;
    int sp = blockIdx.x & 7;
    int s, e;
    {
        int lo = 0, hi = N_NODES;
        while (lo < hi) { int mid = (lo + hi) >> 1; if (batch[mid] < g) lo = mid + 1; else hi = mid; }
        s = lo;
        lo = s; hi = N_NODES;
        while (lo < hi) { int mid = (lo + hi) >> 1; if (batch[mid] < g + 1) lo = mid + 1; else hi = mid; }
        e = lo;
    }
    int len = e - s;
    int chunk = (len + POOL_SPLIT - 1) / POOL_SPLIT;
    int ss = s + sp * chunk;
    int ee = min(ss + chunk, e);
    int cp = threadIdx.x & 63;   // channel pair
    int r  = threadIdx.x >> 6;   // 4 rows
    float a0 = 0.f, a1 = 0.f;
    for (int n = ss + r; n < ee; n += 4) {
        unsigned v = *(const unsigned*)&h[(size_t)n * HDIM + cp * 2];
        a0 += bf_lo(v);
        a1 += bf_hi(v);
    }
    __shared__ float red0[4][64], red1[4][64];
    red0[r][cp] = a0; red1[r][cp] = a1;
    __syncthreads();
    if (r == 0) {
#pragma unroll
        for (int j = 1; j < 4; ++j) { a0 += red0[j][cp]; a1 += red1[j][cp]; }
        atomicAdd(&pool[g * HDIM + cp * 2], a0);
        atomicAdd(&pool[g * HDIM + cp * 2 + 1], a1);
    }
    if (threadIdx.x == 0 && ee > ss) atomicAdd(&counts[g], (float)(ee - ss));
}

// ---------------- tail: mean -> LSTM(seq=1) -> attn(v passthrough) -> MLP ----------------

__global__ __launch_bounds__(128) void k_tail(const float* __restrict__ pool,
                                              const float* __restrict__ counts,
                                              const float* __restrict__ w_ih,
                                              const float* __restrict__ b_ih,
                                              const float* __restrict__ b_hh,
                                              const float* __restrict__ attn_in_w,
                                              const float* __restrict__ attn_in_b,
                                              const float* __restrict__ attn_out_w,
                                              const float* __restrict__ attn_out_b,
                                              const float* __restrict__ w1,
                                              const float* __restrict__ b1,
                                              const float* __restrict__ w2,
                                              const float* __restrict__ b2,
                                              float* __restrict__ out) {
    __shared__ float ge[128], hsr[128], vv[128], fe[128], zz[64];
    int g = blockIdx.x, t = threadIdx.x;
    float cnt = fmaxf(counts[g], 1.0f);
    ge[t] = pool[g * HDIM + t] / cnt;
    __syncthreads();
    float gi = 0.f, gg = 0.f, go = 0.f;
    for (int k = 0; k < 128; ++k) {
        float xv = ge[k];
        gi += xv * w_ih[t * HDIM + k];
        gg += xv * w_ih[(256 + t) * HDIM + k];
        go += xv * w_ih[(384 + t) * HDIM + k];
    }
    gi += b_ih[t] + b_hh[t];
    gg += b_ih[256 + t] + b_hh[256 + t];
    go += b_ih[384 + t] + b_hh[384 + t];
    float cc = (1.f / (1.f + expf(-gi))) * tanhf(gg);
    float hv = (1.f / (1.f + expf(-go))) * tanhf(cc);
    hsr[t] = hv;
    __syncthreads();
    float va = attn_in_b[256 + t];
    for (int k = 0; k < 128; ++k) va += hsr[k] * attn_in_w[(256 + t) * HDIM + k];
    vv[t] = va;
    __syncthreads();
    float fv = attn_out_b[t];
    for (int k = 0; k < 128; ++k) fv += vv[k] * attn_out_w[t * HDIM + k];
    fe[t] = fv;
    __syncthreads();
    if (t < 64) {
        float zv = b1[t];
        for (int k = 0; k < 128; ++k) zv += fe[k] * w1[t * HDIM + k];
        zz[t] = fmaxf(zv, 0.f);
    }
    __syncthreads();
    if (t < NCLS) {
        float ov = b2[t];
        for (int k = 0; k < 64; ++k) ov += zz[k] * w2[t * 64 + k];
        out[g * NCLS + t] = ov;
    }
}

// ---------------- launch ----------------

extern "C" void kernel_launch(void* const* d_in, const int* in_sizes, int n_in,
                              void* d_out, int out_size, void* d_ws, size_t ws_size,
                              hipStream_t stream) {
    const float* x          = (const float*)d_in[0];
    const int*   edge_index = (const int*)d_in[1];
    const int*   batch      = (const int*)d_in[2];
    const float* emb_w      = (const float*)d_in[3];
    const float* emb_b      = (const float*)d_in[4];
    const float* gcn_w      = (const float*)d_in[5];
    const float* gcn_b      = (const float*)d_in[6];
    const float* w_ih       = (const float*)d_in[7];
    // d_in[8] = lstm_w_hh (unused: h0 = 0)
    const float* b_ih       = (const float*)d_in[9];
    const float* b_hh       = (const float*)d_in[10];
    const float* attn_in_w  = (const float*)d_in[11];
    const float* attn_in_b  = (const float*)d_in[12];
    const float* attn_out_w = (const float*)d_in[13];
    const float* attn_out_b = (const float*)d_in[14];
    const float* w1         = (const float*)d_in[15];
    const float* b1         = (const float*)d_in[16];
    const float* w2         = (const float*)d_in[17];
    const float* b2         = (const float*)d_in[18];
    float* out = (float*)d_out;

    // ---- workspace layout ----
    int*   iws = (int*)d_ws;
    float* fws = (float*)d_ws;
    int*   hist      = iws;                         // N
    float* dis       = fws + N_NODES;               // N
    int*   row_start = iws + 2 * N_NODES;           // N+1
    int*   cursor    = iws + 3 * N_NODES + 4;       // N
    int*   csrc      = iws + 4 * N_NODES + 8;       // E
    float* csrw      = fws + 4 * N_NODES + 8 + N_EDGES;  // E
    unsigned short* bws   = (unsigned short*)(iws + 4 * N_NODES + 8 + 2 * N_EDGES);
    unsigned short* x_bf  = bws;                                    // N*64
    unsigned short* we_bf = x_bf + (size_t)N_NODES * F_INDIM;       // 128*64
    unsigned short* wg_bf = we_bf + HDIM * F_INDIM;                 // 3*128*128
    unsigned short* hA    = wg_bf + NLAYERS * HDIM * HDIM;          // N*128
    unsigned short* hB    = hA + (size_t)N_NODES * HDIM;            // N*128
    float* pool     = (float*)(hB + (size_t)N_NODES * HDIM);        // 64*128
    float* counts   = pool + NGRAPH * HDIM;                         // 64
    int*   partials = (int*)(counts + NGRAPH);                      // SCAN_BLOCKS

    const int* src = edge_index;
    const int* dst = edge_index + N_EDGES;

    k_init<<<196, 256, 0, stream>>>(hist, pool, counts);
    k_hist<<<(N_EDGES + 255) / 256, 256, 0, stream>>>(dst, hist);
    k_scan1<<<SCAN_BLOCKS, 256, 0, stream>>>(hist, row_start, partials, dis);
    k_scan2<<<1, 256, 0, stream>>>(partials);
    k_scan3<<<SCAN_BLOCKS, 256, 0, stream>>>(row_start, partials, cursor);
    k_scatter<<<(N_EDGES + 255) / 256, 256, 0, stream>>>(src, dst, dis, cursor, csrc, csrw);

    // conversions
    k_cvt<<<(N_NODES * F_INDIM / 4 + 255) / 256, 256, 0, stream>>>(x, x_bf, N_NODES * F_INDIM / 4);
    k_cvt<<<(HDIM * F_INDIM / 4 + 255) / 256, 256, 0, stream>>>(emb_w, we_bf, HDIM * F_INDIM / 4);
    k_cvt<<<(NLAYERS * HDIM * HDIM / 4 + 255) / 256, 256, 0, stream>>>(gcn_w, wg_bf, NLAYERS * HDIM * HDIM / 4);

    int mm_grid = (NTILES + 3) / 4;   // 782
    k_mm<F_INDIM><<<mm_grid, 256, 0, stream>>>(x_bf, we_bf, emb_b, hA);
    for (int l = 0; l < NLAYERS; ++l) {
        k_mm<HDIM><<<mm_grid, 256, 0, stream>>>(hA, wg_bf + l * HDIM * HDIM, nullptr, hB);
        k_gather<<<N_NODES / 4, 256, 0, stream>>>(hB, row_start, csrc, csrw, dis,
                                                  gcn_b + l * HDIM, hA);
    }
    k_pool<<<NGRAPH * POOL_SPLIT, 256, 0, stream>>>(hA, batch, pool, counts);
    k_tail<<<NGRAPH, 128, 0, stream>>>(pool, counts, w_ih, b_ih, b_hh,
                                       attn_in_w, attn_in_b, attn_out_w, attn_out_b,
                                       w1, b1, w2, b2, out);
}

// Round 6
// 284.653 us; speedup vs baseline: 3.1250x; 1.0142x over previous
//
#include <hip/hip_runtime.h>
#include <math.h>

#define N_NODES 50000
#define N_EDGES 640000
#define F_INDIM 64
#define HDIM 128
#define NLAYERS 3
#define NGRAPH 64
#define NCLS 2
#define SCAN_BLOCKS ((N_NODES + 255) / 256)   // 196
#define POOL_SPLIT 8
#define NTILES (N_NODES / 16)                 // 3125 row-tiles (exact)

typedef __attribute__((ext_vector_type(8))) short bf16x8;   // 8 bf16 (4 VGPRs)
typedef __attribute__((ext_vector_type(4))) float f32x4;

__device__ __forceinline__ float bf_lo(unsigned v) { return __uint_as_float(v << 16); }
__device__ __forceinline__ float bf_hi(unsigned v) { return __uint_as_float(v & 0xffff0000u); }
__device__ __forceinline__ unsigned short f2bf(float f) {
    unsigned b = __float_as_uint(f);
    return (unsigned short)((b + 0x7fffu + ((b >> 16) & 1u)) >> 16);   // RNE
}

// ---------------- init / degree / CSR build ----------------

__global__ __launch_bounds__(256) void k_init(int* hist, float* pool, float* counts) {
    int i = blockIdx.x * 256 + threadIdx.x;
    if (i < N_NODES) hist[i] = 0;
    if (i < NGRAPH * HDIM) pool[i] = 0.f;
    if (i < NGRAPH) counts[i] = 0.f;
}

__global__ __launch_bounds__(256) void k_hist(const int* __restrict__ dst, int* __restrict__ hist) {
    int e = blockIdx.x * 256 + threadIdx.x;
    if (e < N_EDGES) atomicAdd(&hist[dst[e]], 1);
}

__global__ __launch_bounds__(256) void k_scan1(const int* __restrict__ hist,
                                               int* __restrict__ row_start,
                                               int* __restrict__ partials,
                                               float* __restrict__ dis) {
    __shared__ int buf[256];
    int i = blockIdx.x * 256 + threadIdx.x;
    int v = (i < N_NODES) ? hist[i] : 0;
    if (i < N_NODES) dis[i] = rsqrtf((float)v + 1.0f);
    buf[threadIdx.x] = v;
    __syncthreads();
#pragma unroll
    for (int off = 1; off < 256; off <<= 1) {
        int t = (threadIdx.x >= off) ? buf[threadIdx.x - off] : 0;
        __syncthreads();
        buf[threadIdx.x] += t;
        __syncthreads();
    }
    if (i < N_NODES) row_start[i] = buf[threadIdx.x] - v;
    if (threadIdx.x == 255) partials[blockIdx.x] = buf[255];
}

__global__ __launch_bounds__(256) void k_scan2(int* __restrict__ partials) {
    __shared__ int buf[256];
    int v = (threadIdx.x < SCAN_BLOCKS) ? partials[threadIdx.x] : 0;
    buf[threadIdx.x] = v;
    __syncthreads();
#pragma unroll
    for (int off = 1; off < 256; off <<= 1) {
        int t = (threadIdx.x >= off) ? buf[threadIdx.x - off] : 0;
        __syncthreads();
        buf[threadIdx.x] += t;
        __syncthreads();
    }
    if (threadIdx.x < SCAN_BLOCKS) partials[threadIdx.x] = buf[threadIdx.x] - v;
}

__global__ __launch_bounds__(256) void k_scan3(int* __restrict__ row_start,
                                               const int* __restrict__ partials,
                                               int* __restrict__ cursor) {
    int i = blockIdx.x * 256 + threadIdx.x;
    if (i < N_NODES) {
        int r = row_start[i] + partials[blockIdx.x];
        row_start[i] = r;
        cursor[i] = r;
    }
    if (i == 0) row_start[N_NODES] = N_EDGES;
}

// packed CSR record: one 8B store per edge (halves write-amplified line traffic)
__global__ __launch_bounds__(256) void k_scatter(const int* __restrict__ src,
                                                 const int* __restrict__ dst,
                                                 const float* __restrict__ dis,
                                                 int* __restrict__ cursor,
                                                 uint2* __restrict__ csr) {
    int e = blockIdx.x * 256 + threadIdx.x;
    if (e >= N_EDGES) return;
    int s = src[e], d = dst[e];
    int pos = atomicAdd(&cursor[d], 1);
    uint2 rec;
    rec.x = (unsigned)s;
    rec.y = __float_as_uint(dis[s] * dis[d]);
    csr[pos] = rec;
}

// ---------------- fp32 -> bf16 conversion (4 elems/thread) ----------------

__global__ __launch_bounds__(256) void k_cvt(const float* __restrict__ src,
                                             unsigned short* __restrict__ dst, int n4) {
    int i = blockIdx.x * 256 + threadIdx.x;
    if (i >= n4) return;
    float4 v = *(const float4*)&src[i * 4];
    unsigned r0 = (unsigned)f2bf(v.x) | ((unsigned)f2bf(v.y) << 16);
    unsigned r1 = (unsigned)f2bf(v.z) | ((unsigned)f2bf(v.w) << 16);
    *(uint2*)&dst[i * 4] = make_uint2(r0, r1);
}

// ---------------- MFMA GEMM: C[M,128] = A[M,K](bf16) @ W[128,K](bf16)^T (+bias) ----------------

template<int K>
__global__ __launch_bounds__(256) void k_mm(const unsigned short* __restrict__ A,
                                            const unsigned short* __restrict__ W,
                                            const float* __restrict__ bias,
                                            unsigned short* __restrict__ C) {
    constexpr int KS = K / 32;
    int lane = threadIdx.x & 63;
    int lg = lane >> 4, lr = lane & 15;
    int cb = (threadIdx.x >> 6) * 32;          // wave col base
    int tile0 = blockIdx.x * 4;

    bf16x8 wf[2][KS];
#pragma unroll
    for (int ct = 0; ct < 2; ++ct)
#pragma unroll
        for (int ks = 0; ks < KS; ++ks)
            wf[ct][ks] = *(const bf16x8*)&W[(size_t)(cb + ct * 16 + lr) * K + ks * 32 + lg * 8];

    float b0 = bias ? bias[cb + lr] : 0.f;
    float b1 = bias ? bias[cb + 16 + lr] : 0.f;

    int ntile = NTILES - tile0; if (ntile > 4) ntile = 4;
    for (int t = 0; t < ntile; ++t) {
        int rb = (tile0 + t) * 16;
        f32x4 acc0 = {0.f, 0.f, 0.f, 0.f}, acc1 = {0.f, 0.f, 0.f, 0.f};
#pragma unroll
        for (int ks = 0; ks < KS; ++ks) {
            bf16x8 af = *(const bf16x8*)&A[(size_t)(rb + lr) * K + ks * 32 + lg * 8];
            acc0 = __builtin_amdgcn_mfma_f32_16x16x32_bf16(af, wf[0][ks], acc0, 0, 0, 0);
            acc1 = __builtin_amdgcn_mfma_f32_16x16x32_bf16(af, wf[1][ks], acc1, 0, 0, 0);
        }
        int row = rb + lg * 4;
#pragma unroll
        for (int j = 0; j < 4; ++j) {
            C[(size_t)(row + j) * HDIM + cb + lr]      = f2bf(acc0[j] + b0);
            C[(size_t)(row + j) * HDIM + cb + 16 + lr] = f2bf(acc1[j] + b1);
        }
    }
}

// ---------------- GCN aggregation (gather over packed CSR, bf16 in/out) ----------------
// wave per node; lanes 0-31 = even edges, lanes 32-63 = odd edges;
// each lane owns a channel quad (4 channels, 8B loads). 4-pair unroll -> 8 edges in flight.

__global__ __launch_bounds__(256) void k_gather(const unsigned short* __restrict__ hw,
                                                const int* __restrict__ row_start,
                                                const uint2* __restrict__ csr,
                                                const float* __restrict__ dis,
                                                const float* __restrict__ bias,
                                                unsigned short* __restrict__ hout) {
    int n = blockIdx.x * 4 + (threadIdx.x >> 6);
    int lane = threadIdx.x & 63;
    int half = lane >> 5;
    int cl = lane & 31;              // channel quad: channels 4*cl .. 4*cl+3
    int beg = row_start[n], end = row_start[n + 1];
    float a0 = 0.f, a1 = 0.f, a2 = 0.f, a3 = 0.f;
    int e = beg;
    for (; e + 8 <= end; e += 8) {
        uint2 rec[4]; uint2 v[4];
#pragma unroll
        for (int u = 0; u < 4; ++u)
            rec[u] = csr[e + 2 * u + half];
#pragma unroll
        for (int u = 0; u < 4; ++u)
            v[u] = *(const uint2*)&hw[(size_t)rec[u].x * HDIM + cl * 4];
#pragma unroll
        for (int u = 0; u < 4; ++u) {
            float w = __uint_as_float(rec[u].y);
            a0 += w * bf_lo(v[u].x);
            a1 += w * bf_hi(v[u].x);
            a2 += w * bf_lo(v[u].y);
            a3 += w * bf_hi(v[u].y);
        }
    }
    for (; e < end; e += 2) {
        int me = e + half;
        bool valid = me < end;
        uint2 rec = valid ? csr[me] : make_uint2((unsigned)n, 0u);
        uint2 v = *(const uint2*)&hw[(size_t)rec.x * HDIM + cl * 4];
        float w = __uint_as_float(rec.y);
        a0 += w * bf_lo(v.x); a1 += w * bf_hi(v.x);
        a2 += w * bf_lo(v.y); a3 += w * bf_hi(v.y);
    }
    // cross-half combine (even-edge partial + odd-edge partial)
    a0 += __shfl_xor(a0, 32); a1 += __shfl_xor(a1, 32);
    a2 += __shfl_xor(a2, 32); a3 += __shfl_xor(a3, 32);
    if (half == 0) {
        float dn = dis[n], sn = dn * dn;
        uint2 vs = *(const uint2*)&hw[(size_t)n * HDIM + cl * 4];
        a0 += sn * bf_lo(vs.x); a1 += sn * bf_hi(vs.x);
        a2 += sn * bf_lo(vs.y); a3 += sn * bf_hi(vs.y);
        float4 b = *(const float4*)&bias[cl * 4];
        a0 = fmaxf(a0 + b.x, 0.f); a1 = fmaxf(a1 + b.y, 0.f);
        a2 = fmaxf(a2 + b.z, 0.f); a3 = fmaxf(a3 + b.w, 0.f);
        uint2 r;
        r.x = (unsigned)f2bf(a0) | ((unsigned)f2bf(a1) << 16);
        r.y = (unsigned)f2bf(a2) | ((unsigned)f2bf(a3) << 16);
        *(uint2*)&hout[(size_t)n * HDIM + cl * 4] = r;
    }
}

// ---------------- mean-pool: 64 graphs x 8 slices, bf16 input ----------------

__global__ __launch_bounds__(256) void k_pool(const unsigned short* __restrict__ h,
                                              const int* __restrict__ batch,
                                              float* __restrict__ pool,
                                              float* __restrict__ counts) {
    int g  = blockIdx.x >> 3;
    int sp = blockIdx.x & 7;
    int s, e;
    {
        int lo = 0, hi = N_NODES;
        while (lo < hi) { int mid = (lo + hi) >> 1; if (batch[mid] < g) lo = mid + 1; else hi = mid; }
        s = lo;
        lo = s; hi = N_NODES;
        while (lo < hi) { int mid = (lo + hi) >> 1; if (batch[mid] < g + 1) lo = mid + 1; else hi = mid; }
        e = lo;
    }
    int len = e - s;
    int chunk = (len + POOL_SPLIT - 1) / POOL_SPLIT;
    int ss = s + sp * chunk;
    int ee = min(ss + chunk, e);
    int cp = threadIdx.x & 63;   // channel pair
    int r  = threadIdx.x >> 6;   // 4 rows
    float a0 = 0.f, a1 = 0.f;
    for (int n = ss + r; n < ee; n += 4) {
        unsigned v = *(const unsigned*)&h[(size_t)n * HDIM + cp * 2];
        a0 += bf_lo(v);
        a1 += bf_hi(v);
    }
    __shared__ float red0[4][64], red1[4][64];
    red0[r][cp] = a0; red1[r][cp] = a1;
    __syncthreads();
    if (r == 0) {
#pragma unroll
        for (int j = 1; j < 4; ++j) { a0 += red0[j][cp]; a1 += red1[j][cp]; }
        atomicAdd(&pool[g * HDIM + cp * 2], a0);
        atomicAdd(&pool[g * HDIM + cp * 2 + 1], a1);
    }
    if (threadIdx.x == 0 && ee > ss) atomicAdd(&counts[g], (float)(ee - ss));
}

// ---------------- tail: mean -> LSTM(seq=1) -> attn(v passthrough) -> MLP ----------------

__global__ __launch_bounds__(128) void k_tail(const float* __restrict__ pool,
                                              const float* __restrict__ counts,
                                              const float* __restrict__ w_ih,
                                              const float* __restrict__ b_ih,
                                              const float* __restrict__ b_hh,
                                              const float* __restrict__ attn_in_w,
                                              const float* __restrict__ attn_in_b,
                                              const float* __restrict__ attn_out_w,
                                              const float* __restrict__ attn_out_b,
                                              const float* __restrict__ w1,
                                              const float* __restrict__ b1,
                                              const float* __restrict__ w2,
                                              const float* __restrict__ b2,
                                              float* __restrict__ out) {
    __shared__ float ge[128], hsr[128], vv[128], fe[128], zz[64];
    int g = blockIdx.x, t = threadIdx.x;
    float cnt = fmaxf(counts[g], 1.0f);
    ge[t] = pool[g * HDIM + t] / cnt;
    __syncthreads();
    float gi = 0.f, gg = 0.f, go = 0.f;
    for (int k = 0; k < 128; ++k) {
        float xv = ge[k];
        gi += xv * w_ih[t * HDIM + k];
        gg += xv * w_ih[(256 + t) * HDIM + k];
        go += xv * w_ih[(384 + t) * HDIM + k];
    }
    gi += b_ih[t] + b_hh[t];
    gg += b_ih[256 + t] + b_hh[256 + t];
    go += b_ih[384 + t] + b_hh[384 + t];
    float cc = (1.f / (1.f + expf(-gi))) * tanhf(gg);
    float hv = (1.f / (1.f + expf(-go))) * tanhf(cc);
    hsr[t] = hv;
    __syncthreads();
    float va = attn_in_b[256 + t];
    for (int k = 0; k < 128; ++k) va += hsr[k] * attn_in_w[(256 + t) * HDIM + k];
    vv[t] = va;
    __syncthreads();
    float fv = attn_out_b[t];
    for (int k = 0; k < 128; ++k) fv += vv[k] * attn_out_w[t * HDIM + k];
    fe[t] = fv;
    __syncthreads();
    if (t < 64) {
        float zv = b1[t];
        for (int k = 0; k < 128; ++k) zv += fe[k] * w1[t * HDIM + k];
        zz[t] = fmaxf(zv, 0.f);
    }
    __syncthreads();
    if (t < NCLS) {
        float ov = b2[t];
        for (int k = 0; k < 64; ++k) ov += zz[k] * w2[t * 64 + k];
        out[g * NCLS + t] = ov;
    }
}

// ---------------- launch ----------------

extern "C" void kernel_launch(void* const* d_in, const int* in_sizes, int n_in,
                              void* d_out, int out_size, void* d_ws, size_t ws_size,
                              hipStream_t stream) {
    const float* x          = (const float*)d_in[0];
    const int*   edge_index = (const int*)d_in[1];
    const int*   batch      = (const int*)d_in[2];
    const float* emb_w      = (const float*)d_in[3];
    const float* emb_b      = (const float*)d_in[4];
    const float* gcn_w      = (const float*)d_in[5];
    const float* gcn_b      = (const float*)d_in[6];
    const float* w_ih       = (const float*)d_in[7];
    // d_in[8] = lstm_w_hh (unused: h0 = 0)
    const float* b_ih       = (const float*)d_in[9];
    const float* b_hh       = (const float*)d_in[10];
    const float* attn_in_w  = (const float*)d_in[11];
    const float* attn_in_b  = (const float*)d_in[12];
    const float* attn_out_w = (const float*)d_in[13];
    const float* attn_out_b = (const float*)d_in[14];
    const float* w1         = (const float*)d_in[15];
    const float* b1         = (const float*)d_in[16];
    const float* w2         = (const float*)d_in[17];
    const float* b2         = (const float*)d_in[18];
    float* out = (float*)d_out;

    // ---- workspace layout ----
    int*   iws = (int*)d_ws;
    float* fws = (float*)d_ws;
    int*   hist      = iws;                         // N
    float* dis       = fws + N_NODES;               // N
    int*   row_start = iws + 2 * N_NODES;           // N+1
    int*   cursor    = iws + 3 * N_NODES + 4;       // N
    uint2* csr       = (uint2*)(iws + 4 * N_NODES + 8);   // E records (8B, byte off 800032 %8==0)
    unsigned short* bws   = (unsigned short*)(iws + 4 * N_NODES + 8 + 2 * N_EDGES);
    unsigned short* x_bf  = bws;                                    // N*64
    unsigned short* we_bf = x_bf + (size_t)N_NODES * F_INDIM;       // 128*64
    unsigned short* wg_bf = we_bf + HDIM * F_INDIM;                 // 3*128*128
    unsigned short* hA    = wg_bf + NLAYERS * HDIM * HDIM;          // N*128
    unsigned short* hB    = hA + (size_t)N_NODES * HDIM;            // N*128
    float* pool     = (float*)(hB + (size_t)N_NODES * HDIM);        // 64*128
    float* counts   = pool + NGRAPH * HDIM;                         // 64
    int*   partials = (int*)(counts + NGRAPH);                      // SCAN_BLOCKS

    const int* src = edge_index;
    const int* dst = edge_index + N_EDGES;

    k_init<<<196, 256, 0, stream>>>(hist, pool, counts);
    k_hist<<<(N_EDGES + 255) / 256, 256, 0, stream>>>(dst, hist);
    k_scan1<<<SCAN_BLOCKS, 256, 0, stream>>>(hist, row_start, partials, dis);
    k_scan2<<<1, 256, 0, stream>>>(partials);
    k_scan3<<<SCAN_BLOCKS, 256, 0, stream>>>(row_start, partials, cursor);
    k_scatter<<<(N_EDGES + 255) / 256, 256, 0, stream>>>(src, dst, dis, cursor, csr);

    // conversions
    k_cvt<<<(N_NODES * F_INDIM / 4 + 255) / 256, 256, 0, stream>>>(x, x_bf, N_NODES * F_INDIM / 4);
    k_cvt<<<(HDIM * F_INDIM / 4 + 255) / 256, 256, 0, stream>>>(emb_w, we_bf, HDIM * F_INDIM / 4);
    k_cvt<<<(NLAYERS * HDIM * HDIM / 4 + 255) / 256, 256, 0, stream>>>(gcn_w, wg_bf, NLAYERS * HDIM * HDIM / 4);

    int mm_grid = (NTILES + 3) / 4;   // 782
    k_mm<F_INDIM><<<mm_grid, 256, 0, stream>>>(x_bf, we_bf, emb_b, hA);
    for (int l = 0; l < NLAYERS; ++l) {
        k_mm<HDIM><<<mm_grid, 256, 0, stream>>>(hA, wg_bf + l * HDIM * HDIM, nullptr, hB);
        k_gather<<<N_NODES / 4, 256, 0, stream>>>(hB, row_start, csr, dis,
                                                  gcn_b + l * HDIM, hA);
    }
    k_pool<<<NGRAPH * POOL_SPLIT, 256, 0, stream>>>(hA, batch, pool, counts);
    k_tail<<<NGRAPH, 128, 0, stream>>>(pool, counts, w_ih, b_ih, b_hh,
                                       attn_in_w, attn_in_b, attn_out_w, attn_out_b,
                                       w1, b1, w2, b2, out);
}

// Round 7
// 267.245 us; speedup vs baseline: 3.3286x; 1.0651x over previous
//
#include <hip/hip_runtime.h>
#include <math.h>

#define N_NODES 50000
#define N_EDGES 640000
#define F_INDIM 64
#define HDIM 128
#define NLAYERS 3
#define NGRAPH 64
#define NCLS 2
#define SCAN_BLOCKS ((N_NODES + 255) / 256)   // 196
#define POOL_SPLIT 8
#define NTILES (N_NODES / 16)                 // 3125 row-tiles (exact)

typedef __attribute__((ext_vector_type(8))) short bf16x8;   // 8 bf16 (4 VGPRs)
typedef __attribute__((ext_vector_type(4))) float f32x4;

__device__ __forceinline__ float bf_lo(unsigned v) { return __uint_as_float(v << 16); }
__device__ __forceinline__ float bf_hi(unsigned v) { return __uint_as_float(v & 0xffff0000u); }
__device__ __forceinline__ unsigned short f2bf(float f) {
    unsigned b = __float_as_uint(f);
    return (unsigned short)((b + 0x7fffu + ((b >> 16) & 1u)) >> 16);   // RNE
}

// ---------------- init / degree / CSR build ----------------

__global__ __launch_bounds__(256) void k_init(int* cnt, float* pool, float* counts) {
    int i = blockIdx.x * 256 + threadIdx.x;
    if (i < N_NODES) cnt[i] = 0;
    if (i < NGRAPH * HDIM) pool[i] = 0.f;
    if (i < NGRAPH) counts[i] = 0.f;
}

// single atomic pass: produces within-dst rank AND the degree histogram (in cnt)
__global__ __launch_bounds__(256) void k_rank(const int* __restrict__ dst,
                                              int* __restrict__ cnt,
                                              int* __restrict__ rank) {
    int e = blockIdx.x * 256 + threadIdx.x;
    if (e < N_EDGES) rank[e] = atomicAdd(&cnt[dst[e]], 1);
}

__global__ __launch_bounds__(256) void k_scan1(const int* __restrict__ hist,
                                               int* __restrict__ row_start,
                                               int* __restrict__ partials,
                                               float* __restrict__ dis) {
    __shared__ int buf[256];
    int i = blockIdx.x * 256 + threadIdx.x;
    int v = (i < N_NODES) ? hist[i] : 0;
    if (i < N_NODES) dis[i] = rsqrtf((float)v + 1.0f);
    buf[threadIdx.x] = v;
    __syncthreads();
#pragma unroll
    for (int off = 1; off < 256; off <<= 1) {
        int t = (threadIdx.x >= off) ? buf[threadIdx.x - off] : 0;
        __syncthreads();
        buf[threadIdx.x] += t;
        __syncthreads();
    }
    if (i < N_NODES) row_start[i] = buf[threadIdx.x] - v;
    if (threadIdx.x == 255) partials[blockIdx.x] = buf[255];
}

__global__ __launch_bounds__(256) void k_scan2(int* __restrict__ partials) {
    __shared__ int buf[256];
    int v = (threadIdx.x < SCAN_BLOCKS) ? partials[threadIdx.x] : 0;
    buf[threadIdx.x] = v;
    __syncthreads();
#pragma unroll
    for (int off = 1; off < 256; off <<= 1) {
        int t = (threadIdx.x >= off) ? buf[threadIdx.x - off] : 0;
        __syncthreads();
        buf[threadIdx.x] += t;
        __syncthreads();
    }
    if (threadIdx.x < SCAN_BLOCKS) partials[threadIdx.x] = buf[threadIdx.x] - v;
}

__global__ __launch_bounds__(256) void k_scan3(int* __restrict__ row_start,
                                               const int* __restrict__ partials) {
    int i = blockIdx.x * 256 + threadIdx.x;
    if (i < N_NODES) row_start[i] += partials[blockIdx.x];
    if (i == 0) row_start[N_NODES] = N_EDGES;
}

// atomic-free placement: position = row_start[dst] + rank; one 8B store per edge
__global__ __launch_bounds__(256) void k_place(const int* __restrict__ src,
                                               const int* __restrict__ dst,
                                               const int* __restrict__ rank,
                                               const float* __restrict__ dis,
                                               const int* __restrict__ row_start,
                                               uint2* __restrict__ csr) {
    int e = blockIdx.x * 256 + threadIdx.x;
    if (e >= N_EDGES) return;
    int s = src[e], d = dst[e];
    uint2 rec;
    rec.x = (unsigned)s;
    rec.y = __float_as_uint(dis[s] * dis[d]);
    csr[row_start[d] + rank[e]] = rec;
}

// ---------------- fp32 -> bf16 conversion (4 elems/thread) ----------------

__global__ __launch_bounds__(256) void k_cvt(const float* __restrict__ src,
                                             unsigned short* __restrict__ dst, int n4) {
    int i = blockIdx.x * 256 + threadIdx.x;
    if (i >= n4) return;
    float4 v = *(const float4*)&src[i * 4];
    unsigned r0 = (unsigned)f2bf(v.x) | ((unsigned)f2bf(v.y) << 16);
    unsigned r1 = (unsigned)f2bf(v.z) | ((unsigned)f2bf(v.w) << 16);
    *(uint2*)&dst[i * 4] = make_uint2(r0, r1);
}

// ---------------- MFMA GEMM: C[M,128] = A[M,K](bf16) @ W[128,K](bf16)^T (+bias) ----------------

template<int K>
__global__ __launch_bounds__(256) void k_mm(const unsigned short* __restrict__ A,
                                            const unsigned short* __restrict__ W,
                                            const float* __restrict__ bias,
                                            unsigned short* __restrict__ C) {
    constexpr int KS = K / 32;
    int lane = threadIdx.x & 63;
    int lg = lane >> 4, lr = lane & 15;
    int cb = (threadIdx.x >> 6) * 32;          // wave col base
    int tile0 = blockIdx.x * 4;

    bf16x8 wf[2][KS];
#pragma unroll
    for (int ct = 0; ct < 2; ++ct)
#pragma unroll
        for (int ks = 0; ks < KS; ++ks)
            wf[ct][ks] = *(const bf16x8*)&W[(size_t)(cb + ct * 16 + lr) * K + ks * 32 + lg * 8];

    float b0 = bias ? bias[cb + lr] : 0.f;
    float b1 = bias ? bias[cb + 16 + lr] : 0.f;

    int ntile = NTILES - tile0; if (ntile > 4) ntile = 4;
    for (int t = 0; t < ntile; ++t) {
        int rb = (tile0 + t) * 16;
        f32x4 acc0 = {0.f, 0.f, 0.f, 0.f}, acc1 = {0.f, 0.f, 0.f, 0.f};
#pragma unroll
        for (int ks = 0; ks < KS; ++ks) {
            bf16x8 af = *(const bf16x8*)&A[(size_t)(rb + lr) * K + ks * 32 + lg * 8];
            acc0 = __builtin_amdgcn_mfma_f32_16x16x32_bf16(af, wf[0][ks], acc0, 0, 0, 0);
            acc1 = __builtin_amdgcn_mfma_f32_16x16x32_bf16(af, wf[1][ks], acc1, 0, 0, 0);
        }
        int row = rb + lg * 4;
#pragma unroll
        for (int j = 0; j < 4; ++j) {
            C[(size_t)(row + j) * HDIM + cb + lr]      = f2bf(acc0[j] + b0);
            C[(size_t)(row + j) * HDIM + cb + 16 + lr] = f2bf(acc1[j] + b1);
        }
    }
}

// ---------------- GCN aggregation (gather over packed CSR, bf16 in/out) ----------------
// wave per node; lanes 0-31 = even edges, lanes 32-63 = odd edges;
// each lane owns a channel quad (4 channels, 8B loads). 8-pair unroll -> 16 edges in flight.

__global__ __launch_bounds__(256) void k_gather(const unsigned short* __restrict__ hw,
                                                const int* __restrict__ row_start,
                                                const uint2* __restrict__ csr,
                                                const float* __restrict__ dis,
                                                const float* __restrict__ bias,
                                                unsigned short* __restrict__ hout) {
    int n = blockIdx.x * 4 + (threadIdx.x >> 6);
    int lane = threadIdx.x & 63;
    int half = lane >> 5;
    int cl = lane & 31;              // channel quad: channels 4*cl .. 4*cl+3
    int beg = row_start[n], end = row_start[n + 1];
    float a0 = 0.f, a1 = 0.f, a2 = 0.f, a3 = 0.f;
    int e = beg;
    for (; e + 16 <= end; e += 16) {
        uint2 rec[8]; uint2 v[8];
#pragma unroll
        for (int u = 0; u < 8; ++u)
            rec[u] = csr[e + 2 * u + half];
#pragma unroll
        for (int u = 0; u < 8; ++u)
            v[u] = *(const uint2*)&hw[(size_t)rec[u].x * HDIM + cl * 4];
#pragma unroll
        for (int u = 0; u < 8; ++u) {
            float w = __uint_as_float(rec[u].y);
            a0 += w * bf_lo(v[u].x);
            a1 += w * bf_hi(v[u].x);
            a2 += w * bf_lo(v[u].y);
            a3 += w * bf_hi(v[u].y);
        }
    }
    for (; e + 8 <= end; e += 8) {
        uint2 rec[4]; uint2 v[4];
#pragma unroll
        for (int u = 0; u < 4; ++u)
            rec[u] = csr[e + 2 * u + half];
#pragma unroll
        for (int u = 0; u < 4; ++u)
            v[u] = *(const uint2*)&hw[(size_t)rec[u].x * HDIM + cl * 4];
#pragma unroll
        for (int u = 0; u < 4; ++u) {
            float w = __uint_as_float(rec[u].y);
            a0 += w * bf_lo(v[u].x);
            a1 += w * bf_hi(v[u].x);
            a2 += w * bf_lo(v[u].y);
            a3 += w * bf_hi(v[u].y);
        }
    }
    for (; e < end; e += 2) {
        int me = e + half;
        bool valid = me < end;
        uint2 rec = valid ? csr[me] : make_uint2((unsigned)n, 0u);
        uint2 v = *(const uint2*)&hw[(size_t)rec.x * HDIM + cl * 4];
        float w = __uint_as_float(rec.y);
        a0 += w * bf_lo(v.x); a1 += w * bf_hi(v.x);
        a2 += w * bf_lo(v.y); a3 += w * bf_hi(v.y);
    }
    // cross-half combine (even-edge partial + odd-edge partial)
    a0 += __shfl_xor(a0, 32); a1 += __shfl_xor(a1, 32);
    a2 += __shfl_xor(a2, 32); a3 += __shfl_xor(a3, 32);
    if (half == 0) {
        float dn = dis[n], sn = dn * dn;
        uint2 vs = *(const uint2*)&hw[(size_t)n * HDIM + cl * 4];
        a0 += sn * bf_lo(vs.x); a1 += sn * bf_hi(vs.x);
        a2 += sn * bf_lo(vs.y); a3 += sn * bf_hi(vs.y);
        float4 b = *(const float4*)&bias[cl * 4];
        a0 = fmaxf(a0 + b.x, 0.f); a1 = fmaxf(a1 + b.y, 0.f);
        a2 = fmaxf(a2 + b.z, 0.f); a3 = fmaxf(a3 + b.w, 0.f);
        uint2 r;
        r.x = (unsigned)f2bf(a0) | ((unsigned)f2bf(a1) << 16);
        r.y = (unsigned)f2bf(a2) | ((unsigned)f2bf(a3) << 16);
        *(uint2*)&hout[(size_t)n * HDIM + cl * 4] = r;
    }
}

// ---------------- mean-pool: 64 graphs x 8 slices, bf16 input ----------------

__global__ __launch_bounds__(256) void k_pool(const unsigned short* __restrict__ h,
                                              const int* __restrict__ batch,
                                              float* __restrict__ pool,
                                              float* __restrict__ counts) {
    int g  = blockIdx.x >> 3;
    int sp = blockIdx.x & 7;
    int s, e;
    {
        int lo = 0, hi = N_NODES;
        while (lo < hi) { int mid = (lo + hi) >> 1; if (batch[mid] < g) lo = mid + 1; else hi = mid; }
        s = lo;
        lo = s; hi = N_NODES;
        while (lo < hi) { int mid = (lo + hi) >> 1; if (batch[mid] < g + 1) lo = mid + 1; else hi = mid; }
        e = lo;
    }
    int len = e - s;
    int chunk = (len + POOL_SPLIT - 1) / POOL_SPLIT;
    int ss = s + sp * chunk;
    int ee = min(ss + chunk, e);
    int cp = threadIdx.x & 63;   // channel pair
    int r  = threadIdx.x >> 6;   // 4 rows
    float a0 = 0.f, a1 = 0.f;
    for (int n = ss + r; n < ee; n += 4) {
        unsigned v = *(const unsigned*)&h[(size_t)n * HDIM + cp * 2];
        a0 += bf_lo(v);
        a1 += bf_hi(v);
    }
    __shared__ float red0[4][64], red1[4][64];
    red0[r][cp] = a0; red1[r][cp] = a1;
    __syncthreads();
    if (r == 0) {
#pragma unroll
        for (int j = 1; j < 4; ++j) { a0 += red0[j][cp]; a1 += red1[j][cp]; }
        atomicAdd(&pool[g * HDIM + cp * 2], a0);
        atomicAdd(&pool[g * HDIM + cp * 2 + 1], a1);
    }
    if (threadIdx.x == 0 && ee > ss) atomicAdd(&counts[g], (float)(ee - ss));
}

// ---------------- tail: mean -> LSTM(seq=1) -> attn(v passthrough) -> MLP ----------------

__global__ __launch_bounds__(128) void k_tail(const float* __restrict__ pool,
                                              const float* __restrict__ counts,
                                              const float* __restrict__ w_ih,
                                              const float* __restrict__ b_ih,
                                              const float* __restrict__ b_hh,
                                              const float* __restrict__ attn_in_w,
                                              const float* __restrict__ attn_in_b,
                                              const float* __restrict__ attn_out_w,
                                              const float* __restrict__ attn_out_b,
                                              const float* __restrict__ w1,
                                              const float* __restrict__ b1,
                                              const float* __restrict__ w2,
                                              const float* __restrict__ b2,
                                              float* __restrict__ out) {
    __shared__ float ge[128], hsr[128], vv[128], fe[128], zz[64];
    int g = blockIdx.x, t = threadIdx.x;
    float cnt = fmaxf(counts[g], 1.0f);
    ge[t] = pool[g * HDIM + t] / cnt;
    __syncthreads();
    float gi = 0.f, gg = 0.f, go = 0.f;
    for (int k = 0; k < 128; ++k) {
        float xv = ge[k];
        gi += xv * w_ih[t * HDIM + k];
        gg += xv * w_ih[(256 + t) * HDIM + k];
        go += xv * w_ih[(384 + t) * HDIM + k];
    }
    gi += b_ih[t] + b_hh[t];
    gg += b_ih[256 + t] + b_hh[256 + t];
    go += b_ih[384 + t] + b_hh[384 + t];
    float cc = (1.f / (1.f + expf(-gi))) * tanhf(gg);
    float hv = (1.f / (1.f + expf(-go))) * tanhf(cc);
    hsr[t] = hv;
    __syncthreads();
    float va = attn_in_b[256 + t];
    for (int k = 0; k < 128; ++k) va += hsr[k] * attn_in_w[(256 + t) * HDIM + k];
    vv[t] = va;
    __syncthreads();
    float fv = attn_out_b[t];
    for (int k = 0; k < 128; ++k) fv += vv[k] * attn_out_w[t * HDIM + k];
    fe[t] = fv;
    __syncthreads();
    if (t < 64) {
        float zv = b1[t];
        for (int k = 0; k < 128; ++k) zv += fe[k] * w1[t * HDIM + k];
        zz[t] = fmaxf(zv, 0.f);
    }
    __syncthreads();
    if (t < NCLS) {
        float ov = b2[t];
        for (int k = 0; k < 64; ++k) ov += zz[k] * w2[t * 64 + k];
        out[g * NCLS + t] = ov;
    }
}

// ---------------- launch ----------------

extern "C" void kernel_launch(void* const* d_in, const int* in_sizes, int n_in,
                              void* d_out, int out_size, void* d_ws, size_t ws_size,
                              hipStream_t stream) {
    const float* x          = (const float*)d_in[0];
    const int*   edge_index = (const int*)d_in[1];
    const int*   batch      = (const int*)d_in[2];
    const float* emb_w      = (const float*)d_in[3];
    const float* emb_b      = (const float*)d_in[4];
    const float* gcn_w      = (const float*)d_in[5];
    const float* gcn_b      = (const float*)d_in[6];
    const float* w_ih       = (const float*)d_in[7];
    // d_in[8] = lstm_w_hh (unused: h0 = 0)
    const float* b_ih       = (const float*)d_in[9];
    const float* b_hh       = (const float*)d_in[10];
    const float* attn_in_w  = (const float*)d_in[11];
    const float* attn_in_b  = (const float*)d_in[12];
    const float* attn_out_w = (const float*)d_in[13];
    const float* attn_out_b = (const float*)d_in[14];
    const float* w1         = (const float*)d_in[15];
    const float* b1         = (const float*)d_in[16];
    const float* w2         = (const float*)d_in[17];
    const float* b2         = (const float*)d_in[18];
    float* out = (float*)d_out;

    // ---- workspace layout (words) ----
    int*   iws = (int*)d_ws;
    float* fws = (float*)d_ws;
    int*   cnt       = iws;                          // N   (degree histogram)
    float* dis       = fws + N_NODES;                // N
    int*   row_start = iws + 2 * N_NODES;            // N+1 (pad to 3N+4)
    int*   rank      = iws + 3 * N_NODES + 4;        // E
    uint2* csr       = (uint2*)(iws + 3 * N_NODES + 4 + N_EDGES);  // E recs (byte 3160016 %8==0)
    unsigned short* bws   = (unsigned short*)(iws + 3 * N_NODES + 4 + N_EDGES + 2 * N_EDGES);
    unsigned short* x_bf  = bws;                                    // N*64  (byte 8280016 %16==0)
    unsigned short* we_bf = x_bf + (size_t)N_NODES * F_INDIM;       // 128*64
    unsigned short* wg_bf = we_bf + HDIM * F_INDIM;                 // 3*128*128
    unsigned short* hA    = wg_bf + NLAYERS * HDIM * HDIM;          // N*128
    unsigned short* hB    = hA + (size_t)N_NODES * HDIM;            // N*128
    float* pool     = (float*)(hB + (size_t)N_NODES * HDIM);        // 64*128
    float* counts   = pool + NGRAPH * HDIM;                         // 64
    int*   partials = (int*)(counts + NGRAPH);                      // SCAN_BLOCKS

    const int* src = edge_index;
    const int* dst = edge_index + N_EDGES;

    k_init<<<196, 256, 0, stream>>>(cnt, pool, counts);
    k_rank<<<(N_EDGES + 255) / 256, 256, 0, stream>>>(dst, cnt, rank);
    k_scan1<<<SCAN_BLOCKS, 256, 0, stream>>>(cnt, row_start, partials, dis);
    k_scan2<<<1, 256, 0, stream>>>(partials);
    k_scan3<<<SCAN_BLOCKS, 256, 0, stream>>>(row_start, partials);
    k_place<<<(N_EDGES + 255) / 256, 256, 0, stream>>>(src, dst, rank, dis, row_start, csr);

    // conversions
    k_cvt<<<(N_NODES * F_INDIM / 4 + 255) / 256, 256, 0, stream>>>(x, x_bf, N_NODES * F_INDIM / 4);
    k_cvt<<<(HDIM * F_INDIM / 4 + 255) / 256, 256, 0, stream>>>(emb_w, we_bf, HDIM * F_INDIM / 4);
    k_cvt<<<(NLAYERS * HDIM * HDIM / 4 + 255) / 256, 256, 0, stream>>>(gcn_w, wg_bf, NLAYERS * HDIM * HDIM / 4);

    int mm_grid = (NTILES + 3) / 4;   // 782
    k_mm<F_INDIM><<<mm_grid, 256, 0, stream>>>(x_bf, we_bf, emb_b, hA);
    for (int l = 0; l < NLAYERS; ++l) {
        k_mm<HDIM><<<mm_grid, 256, 0, stream>>>(hA, wg_bf + l * HDIM * HDIM, nullptr, hB);
        k_gather<<<N_NODES / 4, 256, 0, stream>>>(hB, row_start, csr, dis,
                                                  gcn_b + l * HDIM, hA);
    }
    k_pool<<<NGRAPH * POOL_SPLIT, 256, 0, stream>>>(hA, batch, pool, counts);
    k_tail<<<NGRAPH, 128, 0, stream>>>(pool, counts, w_ih, b_ih, b_hh,
                                       attn_in_w, attn_in_b, attn_out_w, attn_out_b,
                                       w1, b1, w2, b2, out);
}

// Round 8
// 263.000 us; speedup vs baseline: 3.3823x; 1.0161x over previous
//
#include <hip/hip_runtime.h>
#include <math.h>

#define N_NODES 50000
#define N_EDGES 640000
#define F_INDIM 64
#define HDIM 128
#define NLAYERS 3
#define NGRAPH 64
#define NCLS 2
#define SCAN_BLOCKS ((N_NODES + 255) / 256)   // 196
#define POOL_SPLIT 8
#define NTILES (N_NODES / 16)                 // 3125 row-tiles (exact)

typedef __attribute__((ext_vector_type(8))) short bf16x8;   // 8 bf16 (4 VGPRs)
typedef __attribute__((ext_vector_type(4))) float f32x4;

__device__ __forceinline__ float bf_lo(unsigned v) { return __uint_as_float(v << 16); }
__device__ __forceinline__ float bf_hi(unsigned v) { return __uint_as_float(v & 0xffff0000u); }
__device__ __forceinline__ unsigned short f2bf(float f) {
    unsigned b = __float_as_uint(f);
    return (unsigned short)((b + 0x7fffu + ((b >> 16) & 1u)) >> 16);   // RNE
}

// ---------------- init / degree / CSR build ----------------

__global__ __launch_bounds__(256) void k_init(int* cnt, float* pool, float* counts) {
    int i = blockIdx.x * 256 + threadIdx.x;
    if (i < N_NODES) cnt[i] = 0;
    if (i < NGRAPH * HDIM) pool[i] = 0.f;
    if (i < NGRAPH) counts[i] = 0.f;
}

// single atomic pass: produces within-dst rank AND the degree histogram (in cnt)
__global__ __launch_bounds__(256) void k_rank(const int* __restrict__ dst,
                                              int* __restrict__ cnt,
                                              int* __restrict__ rank) {
    int e = blockIdx.x * 256 + threadIdx.x;
    if (e < N_EDGES) rank[e] = atomicAdd(&cnt[dst[e]], 1);
}

__global__ __launch_bounds__(256) void k_scan1(const int* __restrict__ hist,
                                               int* __restrict__ row_start,
                                               int* __restrict__ partials,
                                               float* __restrict__ dis) {
    __shared__ int buf[256];
    int i = blockIdx.x * 256 + threadIdx.x;
    int v = (i < N_NODES) ? hist[i] : 0;
    if (i < N_NODES) dis[i] = rsqrtf((float)v + 1.0f);
    buf[threadIdx.x] = v;
    __syncthreads();
#pragma unroll
    for (int off = 1; off < 256; off <<= 1) {
        int t = (threadIdx.x >= off) ? buf[threadIdx.x - off] : 0;
        __syncthreads();
        buf[threadIdx.x] += t;
        __syncthreads();
    }
    if (i < N_NODES) row_start[i] = buf[threadIdx.x] - v;
    if (threadIdx.x == 255) partials[blockIdx.x] = buf[255];
}

__global__ __launch_bounds__(256) void k_scan2(int* __restrict__ partials) {
    __shared__ int buf[256];
    int v = (threadIdx.x < SCAN_BLOCKS) ? partials[threadIdx.x] : 0;
    buf[threadIdx.x] = v;
    __syncthreads();
#pragma unroll
    for (int off = 1; off < 256; off <<= 1) {
        int t = (threadIdx.x >= off) ? buf[threadIdx.x - off] : 0;
        __syncthreads();
        buf[threadIdx.x] += t;
        __syncthreads();
    }
    if (threadIdx.x < SCAN_BLOCKS) partials[threadIdx.x] = buf[threadIdx.x] - v;
}

__global__ __launch_bounds__(256) void k_scan3(int* __restrict__ row_start,
                                               const int* __restrict__ partials) {
    int i = blockIdx.x * 256 + threadIdx.x;
    if (i < N_NODES) row_start[i] += partials[blockIdx.x];
    if (i == 0) row_start[N_NODES] = N_EDGES;
}

// atomic-free placement: position = row_start[dst] + rank; one 8B store per edge
__global__ __launch_bounds__(256) void k_place(const int* __restrict__ src,
                                               const int* __restrict__ dst,
                                               const int* __restrict__ rank,
                                               const float* __restrict__ dis,
                                               const int* __restrict__ row_start,
                                               uint2* __restrict__ csr) {
    int e = blockIdx.x * 256 + threadIdx.x;
    if (e >= N_EDGES) return;
    int s = src[e], d = dst[e];
    uint2 rec;
    rec.x = (unsigned)s;
    rec.y = __float_as_uint(dis[s] * dis[d]);
    csr[row_start[d] + rank[e]] = rec;
}

// ---------------- fp32 -> bf16 conversion, all three tensors in one launch ----------------
// regions (in quads of 4 floats): [0,Q1): x -> x_bf ; [Q1,Q2): emb_w ; [Q2,Q3): gcn_w
#define CVT_Q1 (N_NODES * F_INDIM / 4)
#define CVT_Q2 (CVT_Q1 + HDIM * F_INDIM / 4)
#define CVT_Q3 (CVT_Q2 + NLAYERS * HDIM * HDIM / 4)

__global__ __launch_bounds__(256) void k_cvt_all(const float* __restrict__ x,
                                                 const float* __restrict__ emb_w,
                                                 const float* __restrict__ gcn_w,
                                                 unsigned short* __restrict__ dst0) {
    int i = blockIdx.x * 256 + threadIdx.x;
    if (i >= CVT_Q3) return;
    const float* s;
    int off;
    if (i < CVT_Q1)      { s = x;     off = i; }
    else if (i < CVT_Q2) { s = emb_w; off = i - CVT_Q1; }
    else                 { s = gcn_w; off = i - CVT_Q2; }
    float4 v = *(const float4*)&s[off * 4];
    unsigned r0 = (unsigned)f2bf(v.x) | ((unsigned)f2bf(v.y) << 16);
    unsigned r1 = (unsigned)f2bf(v.z) | ((unsigned)f2bf(v.w) << 16);
    *(uint2*)&dst0[i * 4] = make_uint2(r0, r1);
}

// ---------------- MFMA GEMM: C[M,128] = A[M,K](bf16) @ W[128,K](bf16)^T (+bias) ----------------

template<int K>
__global__ __launch_bounds__(256) void k_mm(const unsigned short* __restrict__ A,
                                            const unsigned short* __restrict__ W,
                                            const float* __restrict__ bias,
                                            unsigned short* __restrict__ C) {
    constexpr int KS = K / 32;
    int lane = threadIdx.x & 63;
    int lg = lane >> 4, lr = lane & 15;
    int cb = (threadIdx.x >> 6) * 32;          // wave col base
    int tile0 = blockIdx.x * 4;

    bf16x8 wf[2][KS];
#pragma unroll
    for (int ct = 0; ct < 2; ++ct)
#pragma unroll
        for (int ks = 0; ks < KS; ++ks)
            wf[ct][ks] = *(const bf16x8*)&W[(size_t)(cb + ct * 16 + lr) * K + ks * 32 + lg * 8];

    float b0 = bias ? bias[cb + lr] : 0.f;
    float b1 = bias ? bias[cb + 16 + lr] : 0.f;

    int ntile = NTILES - tile0; if (ntile > 4) ntile = 4;
    for (int t = 0; t < ntile; ++t) {
        int rb = (tile0 + t) * 16;
        f32x4 acc0 = {0.f, 0.f, 0.f, 0.f}, acc1 = {0.f, 0.f, 0.f, 0.f};
#pragma unroll
        for (int ks = 0; ks < KS; ++ks) {
            bf16x8 af = *(const bf16x8*)&A[(size_t)(rb + lr) * K + ks * 32 + lg * 8];
            acc0 = __builtin_amdgcn_mfma_f32_16x16x32_bf16(af, wf[0][ks], acc0, 0, 0, 0);
            acc1 = __builtin_amdgcn_mfma_f32_16x16x32_bf16(af, wf[1][ks], acc1, 0, 0, 0);
        }
        int row = rb + lg * 4;
#pragma unroll
        for (int j = 0; j < 4; ++j) {
            C[(size_t)(row + j) * HDIM + cb + lr]      = f2bf(acc0[j] + b0);
            C[(size_t)(row + j) * HDIM + cb + 16 + lr] = f2bf(acc1[j] + b1);
        }
    }
}

// ---------------- GCN aggregation (gather over packed CSR, bf16 in/out) ----------------
// wave per node; lanes 0-31 = even edges, lanes 32-63 = odd edges;
// each lane owns a channel quad (4 channels, 8B loads).
// single masked 16-edge round per iteration: all loads unconditional (clamped index,
// zeroed weight) -> ~1 dependent latency round for deg<=16 (85% of nodes).

__global__ __launch_bounds__(256) void k_gather(const unsigned short* __restrict__ hw,
                                                const int* __restrict__ row_start,
                                                const uint2* __restrict__ csr,
                                                const float* __restrict__ dis,
                                                const float* __restrict__ bias,
                                                unsigned short* __restrict__ hout) {
    int n = blockIdx.x * 4 + (threadIdx.x >> 6);
    int lane = threadIdx.x & 63;
    int half = lane >> 5;
    int cl = lane & 31;              // channel quad: channels 4*cl .. 4*cl+3
    int beg = row_start[n], end = row_start[n + 1];
    float a0 = 0.f, a1 = 0.f, a2 = 0.f, a3 = 0.f;
    for (int e = beg; e < end; e += 16) {
        unsigned sidx[8]; float w[8]; uint2 v[8];
#pragma unroll
        for (int u = 0; u < 8; ++u) {
            int me = e + 2 * u + half;
            uint2 rec = csr[min(me, end - 1)];
            sidx[u] = rec.x;
            w[u] = (me < end) ? __uint_as_float(rec.y) : 0.f;
        }
#pragma unroll
        for (int u = 0; u < 8; ++u)
            v[u] = *(const uint2*)&hw[(size_t)sidx[u] * HDIM + cl * 4];
#pragma unroll
        for (int u = 0; u < 8; ++u) {
            a0 += w[u] * bf_lo(v[u].x);
            a1 += w[u] * bf_hi(v[u].x);
            a2 += w[u] * bf_lo(v[u].y);
            a3 += w[u] * bf_hi(v[u].y);
        }
    }
    // cross-half combine (even-edge partial + odd-edge partial)
    a0 += __shfl_xor(a0, 32); a1 += __shfl_xor(a1, 32);
    a2 += __shfl_xor(a2, 32); a3 += __shfl_xor(a3, 32);
    if (half == 0) {
        float dn = dis[n], sn = dn * dn;
        uint2 vs = *(const uint2*)&hw[(size_t)n * HDIM + cl * 4];
        a0 += sn * bf_lo(vs.x); a1 += sn * bf_hi(vs.x);
        a2 += sn * bf_lo(vs.y); a3 += sn * bf_hi(vs.y);
        float4 b = *(const float4*)&bias[cl * 4];
        a0 = fmaxf(a0 + b.x, 0.f); a1 = fmaxf(a1 + b.y, 0.f);
        a2 = fmaxf(a2 + b.z, 0.f); a3 = fmaxf(a3 + b.w, 0.f);
        uint2 r;
        r.x = (unsigned)f2bf(a0) | ((unsigned)f2bf(a1) << 16);
        r.y = (unsigned)f2bf(a2) | ((unsigned)f2bf(a3) << 16);
        *(uint2*)&hout[(size_t)n * HDIM + cl * 4] = r;
    }
}

// ---------------- mean-pool: 64 graphs x 8 slices, bf16 input ----------------

__global__ __launch_bounds__(256) void k_pool(const unsigned short* __restrict__ h,
                                              const int* __restrict__ batch,
                                              float* __restrict__ pool,
                                              float* __restrict__ counts) {
    int g  = blockIdx.x >> 3;
    int sp = blockIdx.x & 7;
    int s, e;
    {
        int lo = 0, hi = N_NODES;
        while (lo < hi) { int mid = (lo + hi) >> 1; if (batch[mid] < g) lo = mid + 1; else hi = mid; }
        s = lo;
        lo = s; hi = N_NODES;
        while (lo < hi) { int mid = (lo + hi) >> 1; if (batch[mid] < g + 1) lo = mid + 1; else hi = mid; }
        e = lo;
    }
    int len = e - s;
    int chunk = (len + POOL_SPLIT - 1) / POOL_SPLIT;
    int ss = s + sp * chunk;
    int ee = min(ss + chunk, e);
    int cp = threadIdx.x & 63;   // channel pair
    int r  = threadIdx.x >> 6;   // 4 rows
    float a0 = 0.f, a1 = 0.f;
    for (int n = ss + r; n < ee; n += 4) {
        unsigned v = *(const unsigned*)&h[(size_t)n * HDIM + cp * 2];
        a0 += bf_lo(v);
        a1 += bf_hi(v);
    }
    __shared__ float red0[4][64], red1[4][64];
    red0[r][cp] = a0; red1[r][cp] = a1;
    __syncthreads();
    if (r == 0) {
#pragma unroll
        for (int j = 1; j < 4; ++j) { a0 += red0[j][cp]; a1 += red1[j][cp]; }
        atomicAdd(&pool[g * HDIM + cp * 2], a0);
        atomicAdd(&pool[g * HDIM + cp * 2 + 1], a1);
    }
    if (threadIdx.x == 0 && ee > ss) atomicAdd(&counts[g], (float)(ee - ss));
}

// ---------------- tail: mean -> LSTM(seq=1) -> attn(v passthrough) -> MLP ----------------

__global__ __launch_bounds__(128) void k_tail(const float* __restrict__ pool,
                                              const float* __restrict__ counts,
                                              const float* __restrict__ w_ih,
                                              const float* __restrict__ b_ih,
                                              const float* __restrict__ b_hh,
                                              const float* __restrict__ attn_in_w,
                                              const float* __restrict__ attn_in_b,
                                              const float* __restrict__ attn_out_w,
                                              const float* __restrict__ attn_out_b,
                                              const float* __restrict__ w1,
                                              const float* __restrict__ b1,
                                              const float* __restrict__ w2,
                                              const float* __restrict__ b2,
                                              float* __restrict__ out) {
    __shared__ float ge[128], hsr[128], vv[128], fe[128], zz[64];
    int g = blockIdx.x, t = threadIdx.x;
    float cnt = fmaxf(counts[g], 1.0f);
    ge[t] = pool[g * HDIM + t] / cnt;
    __syncthreads();
    float gi = 0.f, gg = 0.f, go = 0.f;
    for (int k = 0; k < 128; ++k) {
        float xv = ge[k];
        gi += xv * w_ih[t * HDIM + k];
        gg += xv * w_ih[(256 + t) * HDIM + k];
        go += xv * w_ih[(384 + t) * HDIM + k];
    }
    gi += b_ih[t] + b_hh[t];
    gg += b_ih[256 + t] + b_hh[256 + t];
    go += b_ih[384 + t] + b_hh[384 + t];
    float cc = (1.f / (1.f + expf(-gi))) * tanhf(gg);
    float hv = (1.f / (1.f + expf(-go))) * tanhf(cc);
    hsr[t] = hv;
    __syncthreads();
    float va = attn_in_b[256 + t];
    for (int k = 0; k < 128; ++k) va += hsr[k] * attn_in_w[(256 + t) * HDIM + k];
    vv[t] = va;
    __syncthreads();
    float fv = attn_out_b[t];
    for (int k = 0; k < 128; ++k) fv += vv[k] * attn_out_w[t * HDIM + k];
    fe[t] = fv;
    __syncthreads();
    if (t < 64) {
        float zv = b1[t];
        for (int k = 0; k < 128; ++k) zv += fe[k] * w1[t * HDIM + k];
        zz[t] = fmaxf(zv, 0.f);
    }
    __syncthreads();
    if (t < NCLS) {
        float ov = b2[t];
        for (int k = 0; k < 64; ++k) ov += zz[k] * w2[t * 64 + k];
        out[g * NCLS + t] = ov;
    }
}

// ---------------- launch ----------------

extern "C" void kernel_launch(void* const* d_in, const int* in_sizes, int n_in,
                              void* d_out, int out_size, void* d_ws, size_t ws_size,
                              hipStream_t stream) {
    const float* x          = (const float*)d_in[0];
    const int*   edge_index = (const int*)d_in[1];
    const int*   batch      = (const int*)d_in[2];
    const float* emb_w      = (const float*)d_in[3];
    const float* emb_b      = (const float*)d_in[4];
    const float* gcn_w      = (const float*)d_in[5];
    const float* gcn_b      = (const float*)d_in[6];
    const float* w_ih       = (const float*)d_in[7];
    // d_in[8] = lstm_w_hh (unused: h0 = 0)
    const float* b_ih       = (const float*)d_in[9];
    const float* b_hh       = (const float*)d_in[10];
    const float* attn_in_w  = (const float*)d_in[11];
    const float* attn_in_b  = (const float*)d_in[12];
    const float* attn_out_w = (const float*)d_in[13];
    const float* attn_out_b = (const float*)d_in[14];
    const float* w1         = (const float*)d_in[15];
    const float* b1         = (const float*)d_in[16];
    const float* w2         = (const float*)d_in[17];
    const float* b2         = (const float*)d_in[18];
    float* out = (float*)d_out;

    // ---- workspace layout (words) ----
    int*   iws = (int*)d_ws;
    float* fws = (float*)d_ws;
    int*   cnt       = iws;                          // N   (degree histogram)
    float* dis       = fws + N_NODES;                // N
    int*   row_start = iws + 2 * N_NODES;            // N+1 (pad to 3N+4)
    int*   rank      = iws + 3 * N_NODES + 4;        // E
    uint2* csr       = (uint2*)(iws + 3 * N_NODES + 4 + N_EDGES);  // E recs (byte 3160016 %8==0)
    unsigned short* bws   = (unsigned short*)(iws + 3 * N_NODES + 4 + N_EDGES + 2 * N_EDGES);
    unsigned short* x_bf  = bws;                                    // N*64  (byte 8280016 %16==0)
    unsigned short* we_bf = x_bf + (size_t)N_NODES * F_INDIM;       // 128*64  (contiguous with x_bf!)
    unsigned short* wg_bf = we_bf + HDIM * F_INDIM;                 // 3*128*128 (contiguous)
    unsigned short* hA    = wg_bf + NLAYERS * HDIM * HDIM;          // N*128
    unsigned short* hB    = hA + (size_t)N_NODES * HDIM;            // N*128
    float* pool     = (float*)(hB + (size_t)N_NODES * HDIM);        // 64*128
    float* counts   = pool + NGRAPH * HDIM;                         // 64
    int*   partials = (int*)(counts + NGRAPH);                      // SCAN_BLOCKS

    const int* src = edge_index;
    const int* dst = edge_index + N_EDGES;

    k_init<<<196, 256, 0, stream>>>(cnt, pool, counts);
    k_rank<<<(N_EDGES + 255) / 256, 256, 0, stream>>>(dst, cnt, rank);
    k_scan1<<<SCAN_BLOCKS, 256, 0, stream>>>(cnt, row_start, partials, dis);
    k_scan2<<<1, 256, 0, stream>>>(partials);
    k_scan3<<<SCAN_BLOCKS, 256, 0, stream>>>(row_start, partials);
    k_place<<<(N_EDGES + 255) / 256, 256, 0, stream>>>(src, dst, rank, dis, row_start, csr);

    // one fused conversion pass (x_bf / we_bf / wg_bf are contiguous in ws)
    k_cvt_all<<<(CVT_Q3 + 255) / 256, 256, 0, stream>>>(x, emb_w, gcn_w, x_bf);

    int mm_grid = (NTILES + 3) / 4;   // 782
    k_mm<F_INDIM><<<mm_grid, 256, 0, stream>>>(x_bf, we_bf, emb_b, hA);
    for (int l = 0; l < NLAYERS; ++l) {
        k_mm<HDIM><<<mm_grid, 256, 0, stream>>>(hA, wg_bf + l * HDIM * HDIM, nullptr, hB);
        k_gather<<<N_NODES / 4, 256, 0, stream>>>(hB, row_start, csr, dis,
                                                  gcn_b + l * HDIM, hA);
    }
    k_pool<<<NGRAPH * POOL_SPLIT, 256, 0, stream>>>(hA, batch, pool, counts);
    k_tail<<<NGRAPH, 128, 0, stream>>>(pool, counts, w_ih, b_ih, b_hh,
                                       attn_in_w, attn_in_b, attn_out_w, attn_out_b,
                                       w1, b1, w2, b2, out);
}